// Round 5
// baseline (5447.589 us; speedup 1.0000x reference)
//
#include <hip/hip_runtime.h>
#include <hip/hip_bf16.h>
#include <cstddef>
#include <cstdint>

#define NN   2048
#define BB   32
#define TT   24
#define CIN  2
#define HH   64
#define EMBD 16
#define HOR  12
#define XC   (TT*BB*CIN)   // 1536 cols of precomputed A@x
#define PW   4096          // P row width: cols [0,2048)=P2, [2048,4096)=P1

using bfrag  = __attribute__((ext_vector_type(8))) short;   // 8 bf16 = 4 VGPR
using f32x4  = __attribute__((ext_vector_type(4))) float;
using f32x16 = __attribute__((ext_vector_type(16))) float;

static __device__ __forceinline__ short f2bf(float f) {
    __hip_bfloat16 h = __float2bfloat16(f);
    return *reinterpret_cast<short*>(&h);
}
static __device__ __forceinline__ float bf2f(short s) {
    __hip_bfloat16 h;
    *reinterpret_cast<short*>(&h) = s;
    return __bfloat162float(h);
}
static __device__ __forceinline__ unsigned int packsplit(float v) {
    short hb = f2bf(v);
    short lb = f2bf(v - bf2f(hb));
    return (unsigned int)(unsigned short)hb | ((unsigned int)(unsigned short)lb << 16);
}

#define AS1 __attribute__((address_space(1)))
#define AS3 __attribute__((address_space(3)))
static __device__ __forceinline__ void gload16(const short* g, short* l) {
    __builtin_amdgcn_global_load_lds((const AS1 void*)g, (AS3 void*)l, 16, 0, 0);
}

// ---------------- A = softmax(relu(E E^T)) -> split bf16 hi/lo ----------------
__global__ __launch_bounds__(256) void compute_A_kernel(const float* __restrict__ E,
                                                        short* __restrict__ Ahi,
                                                        short* __restrict__ Alo) {
    __shared__ float srow[NN];
    __shared__ float sred[256];
    int row = blockIdx.x;
    float er[EMBD];
#pragma unroll
    for (int k = 0; k < EMBD; ++k) er[k] = E[row*EMBD + k];
    float lmax = -1e30f;
    for (int j = threadIdx.x; j < NN; j += 256) {
        const float* ej = E + j*EMBD;
        float d = 0.f;
#pragma unroll
        for (int k = 0; k < EMBD; ++k) d = fmaf(er[k], ej[k], d);
        d = fmaxf(d, 0.f);
        srow[j] = d;
        lmax = fmaxf(lmax, d);
    }
    sred[threadIdx.x] = lmax;
    __syncthreads();
    for (int s = 128; s > 0; s >>= 1) {
        if (threadIdx.x < s) sred[threadIdx.x] = fmaxf(sred[threadIdx.x], sred[threadIdx.x+s]);
        __syncthreads();
    }
    float rmax = sred[0];
    __syncthreads();
    float lsum = 0.f;
    for (int j = threadIdx.x; j < NN; j += 256) {
        float e = expf(srow[j] - rmax);
        srow[j] = e;
        lsum += e;
    }
    sred[threadIdx.x] = lsum;
    __syncthreads();
    for (int s = 128; s > 0; s >>= 1) {
        if (threadIdx.x < s) sred[threadIdx.x] += sred[threadIdx.x+s];
        __syncthreads();
    }
    float rinv = 1.f / sred[0];
    for (int j = threadIdx.x; j < NN; j += 256) {
        float v = srow[j] * rinv;
        short h = f2bf(v);
        Ahi[(size_t)row*NN + j] = h;
        Alo[(size_t)row*NN + j] = f2bf(v - bf2f(h));
    }
}

// ---------------- build XallT hi/lo: [col=(t*32+b)*2+c][n] ----------------
__global__ void scatter_xall(const float* __restrict__ x,
                             short* __restrict__ hi, short* __restrict__ lo) {
    int idx = blockIdx.x*256 + threadIdx.x;     // col*2048 + n
    int n = idx & (NN-1);
    int col = idx >> 11;
    int c = col & 1, b = (col >> 1) & 31, t = col >> 6;
    float v = x[(size_t)(((size_t)b*TT + t)*NN + n)*CIN + c];
    short h = f2bf(v);
    size_t o = (size_t)col*NN + n;
    hi[o] = h;
    lo[o] = f2bf(v - bf2f(h));
}

// ---------------- W^T split: Wt[j][c] = split(W[rowoff+c][j]) ----------------
__global__ void wsplit_T(const float* __restrict__ W, int rowoff, int Kd,
                         short* __restrict__ hi, short* __restrict__ lo) {
    int id = blockIdx.x*256 + threadIdx.x;      // j*Kd + c
    if (id >= 256*Kd) return;
    int j = id / Kd, c = id - j*Kd;
    float v = W[(size_t)(rowoff + c)*256 + j];
    short h = f2bf(v);
    hi[id] = h;
    lo[id] = f2bf(v - bf2f(h));
}

// ---------------- convX GEMM: f32 out (proven round-3 kernel, runs once) ------
__global__ __launch_bounds__(256, 3) void gc3_gemm(
        const short* __restrict__ Ahi, const short* __restrict__ Alo,
        const short* __restrict__ Bhi, const short* __restrict__ Blo,
        float* __restrict__ Cout, int outStride) {
    __shared__ short As[12288];
    short* AsHi = As;
    short* AsLo = As + 2048;
    short* BsHi = As + 4096;
    short* BsLo = As + 8192;
    const int t = threadIdx.x;
    const int w = t >> 6, lane = t & 63;
    const int wm = w >> 1, wn = w & 1;
    const int fr = lane & 15, fc = lane >> 4;
    const int rowbase = blockIdx.y * 64;
    const int colbase = blockIdx.x * 128;

    const int rp = t >> 3, ql = t & 7;
    const int qs = ql ^ (rp & 7);
    const int srow = rp*2 + (qs >> 2);
    const int sch  = (qs & 3) * 8;
    const short* aHiS = Ahi + (size_t)(rowbase + srow)*NN + sch;
    const short* aLoS = Alo + (size_t)(rowbase + srow)*NN + sch;
    const short* bHiS = Bhi + (size_t)(colbase + srow)*NN + sch;
    const short* bLoS = Blo + (size_t)(colbase + srow)*NN + sch;
    const size_t bHalf = (size_t)64*NN;

    short* aHiD  = AsHi + t*8;
    short* aLoD  = AsLo + t*8;
    short* bHiD0 = BsHi + t*8;
    short* bHiD1 = BsHi + 2048 + t*8;
    short* bLoD0 = BsLo + t*8;
    short* bLoD1 = BsLo + 2048 + t*8;

    auto ldsoff = [](int row, int f) {
        int rr = row >> 1;
        int q = (((row & 1) << 2) | f) ^ (rr & 7);
        return rr*64 + q*8;
    };
    int aoff[2], boff[4];
#pragma unroll
    for (int m = 0; m < 2; ++m) aoff[m] = ldsoff(wm*32 + m*16 + fr, fc);
#pragma unroll
    for (int n = 0; n < 4; ++n) boff[n] = ldsoff(wn*64 + n*16 + fr, fc);

    f32x4 acc[2][4];
#pragma unroll
    for (int m = 0; m < 2; ++m)
#pragma unroll
        for (int n = 0; n < 4; ++n)
#pragma unroll
            for (int r = 0; r < 4; ++r) acc[m][n][r] = 0.f;

    for (int k0 = 0; k0 < NN; k0 += 32) {
        gload16(aHiS, aHiD);
        gload16(aLoS, aLoD);
        gload16(bHiS, bHiD0);
        gload16(bHiS + bHalf, bHiD1);
        gload16(bLoS, bLoD0);
        gload16(bLoS + bHalf, bLoD1);
        aHiS += 32; aLoS += 32; bHiS += 32; bLoS += 32;
        __syncthreads();
        bfrag ah[2], al[2], bh[4], bl[4];
#pragma unroll
        for (int m = 0; m < 2; ++m) {
            ah[m] = *(const bfrag*)(AsHi + aoff[m]);
            al[m] = *(const bfrag*)(AsLo + aoff[m]);
        }
#pragma unroll
        for (int n = 0; n < 4; ++n) {
            bh[n] = *(const bfrag*)(BsHi + boff[n]);
            bl[n] = *(const bfrag*)(BsLo + boff[n]);
        }
#pragma unroll
        for (int m = 0; m < 2; ++m)
#pragma unroll
            for (int n = 0; n < 4; ++n) {
                acc[m][n] = __builtin_amdgcn_mfma_f32_16x16x32_bf16(ah[m], bh[n], acc[m][n], 0, 0, 0);
                acc[m][n] = __builtin_amdgcn_mfma_f32_16x16x32_bf16(ah[m], bl[n], acc[m][n], 0, 0, 0);
                acc[m][n] = __builtin_amdgcn_mfma_f32_16x16x32_bf16(al[m], bh[n], acc[m][n], 0, 0, 0);
            }
        __syncthreads();
    }
#pragma unroll
    for (int m = 0; m < 2; ++m) {
        const int gr = rowbase + wm*32 + m*16 + fc*4;
#pragma unroll
        for (int n = 0; n < 4; ++n) {
            const int gc = colbase + wn*64 + n*16 + fr;
#pragma unroll
            for (int r = 0; r < 4; ++r)
                Cout[(size_t)(gr + r)*outStride + gc] = acc[m][n][r];
        }
    }
}

// ---------------- recurrent GEMM: 32x32x16 frags, 128x256 tile, dbuf 2-phase --
// C written PACKED (hi bf16 | lo bf16) per element.
// LDS per K16 buffer: Ahi[128x16] Alo Bhi[256x16] Blo = 24576 B, dbuf = 48 KB.
// Swizzle: 4-row/128B groups, chunk g' = g ^ ((row>>2)&7); staged pre-swizzled.
__global__ __launch_bounds__(256, 1) void gc32_gemm(
        const short* __restrict__ Ahi, const short* __restrict__ Alo,
        const short* __restrict__ Bhi, const short* __restrict__ Blo,
        unsigned int* __restrict__ Cpk, int outStride) {
    __shared__ short lds[2*12288];
    const int t = threadIdx.x;
    const int w = t >> 6, lane = t & 63;
    const int wm = w >> 1, wn = w & 1;
    const int lr = lane & 31, lc = lane >> 5;
    const int rowbase = blockIdx.y * 128;
    const int colbase = blockIdx.x * 256;

    // staging decode: 6 sweeps x 256 chunks; planes (chunks): Ahi[0,256) Alo[256,512)
    // Bhi[512,1024) Blo[1024,1536). chunk pp in plane: rq=pp>>3, g'=pp&7,
    // g = g'^(rq&7), row = rq*4 + (g>>1), c = g&1 -> src row*NN + c*8 (+k0)
    const short* srcs[6];
#pragma unroll
    for (int s = 0; s < 6; ++s) {
        int p = s*256 + t;
        const short* pbase; int pp;
        if (s == 0)      { pbase = Ahi + (size_t)rowbase*NN; pp = p; }
        else if (s == 1) { pbase = Alo + (size_t)rowbase*NN; pp = p - 256; }
        else if (s < 4)  { pbase = Bhi + (size_t)colbase*NN; pp = p - 512; }
        else             { pbase = Blo + (size_t)colbase*NN; pp = p - 1024; }
        int rq = pp >> 3, g = (pp & 7) ^ (rq & 7);
        int row = rq*4 + (g >> 1), c = g & 1;
        srcs[s] = pbase + (size_t)row*NN + c*8;
    }

    // fragment read offsets (shorts) with matching swizzle
    auto sw = [](int row, int c) {
        int g = (((row & 3) << 1) | c) ^ ((row >> 2) & 7);
        return (row >> 2)*64 + g*8;
    };
    int aoff[2], boff[4];
#pragma unroll
    for (int m = 0; m < 2; ++m) aoff[m] = sw(wm*64 + m*32 + lr, lc);
#pragma unroll
    for (int n = 0; n < 4; ++n) boff[n] = sw(wn*128 + n*32 + lr, lc);

    f32x16 acc[2][4];
#pragma unroll
    for (int m = 0; m < 2; ++m)
#pragma unroll
        for (int n = 0; n < 4; ++n)
#pragma unroll
            for (int r = 0; r < 16; ++r) acc[m][n][r] = 0.f;

    // prologue: stage k=0 into buf0
#pragma unroll
    for (int s = 0; s < 6; ++s)
        gload16(srcs[s], lds + (s*256 + t)*8);
    __syncthreads();

    int cur = 0;
    for (int k0 = 0; k0 < NN; k0 += 16) {
        short* cb = lds + cur*12288;
        if (k0 + 16 < NN) {
            short* nb = lds + (cur^1)*12288;
#pragma unroll
            for (int s = 0; s < 6; ++s)
                gload16(srcs[s] + (k0 + 16), nb + (s*256 + t)*8);
        }
        bfrag ah[2], al[2], bh[4], bl[4];
#pragma unroll
        for (int m = 0; m < 2; ++m) {
            ah[m] = *(const bfrag*)(cb + aoff[m]);
            al[m] = *(const bfrag*)(cb + 2048 + aoff[m]);
        }
#pragma unroll
        for (int n = 0; n < 4; ++n) {
            bh[n] = *(const bfrag*)(cb + 4096 + boff[n]);
            bl[n] = *(const bfrag*)(cb + 8192 + boff[n]);
        }
#pragma unroll
        for (int m = 0; m < 2; ++m)
#pragma unroll
            for (int n = 0; n < 4; ++n) {
                acc[m][n] = __builtin_amdgcn_mfma_f32_32x32x16_bf16(ah[m], bh[n], acc[m][n], 0, 0, 0);
                acc[m][n] = __builtin_amdgcn_mfma_f32_32x32x16_bf16(ah[m], bl[n], acc[m][n], 0, 0, 0);
                acc[m][n] = __builtin_amdgcn_mfma_f32_32x32x16_bf16(al[m], bh[n], acc[m][n], 0, 0, 0);
            }
        __syncthreads();
        cur ^= 1;
    }
    // C/D (32x32): col = lane&31, row = (reg&3) + 8*(reg>>2) + 4*(lane>>5)
#pragma unroll
    for (int m = 0; m < 2; ++m) {
        const int gr0 = rowbase + wm*64 + m*32 + 4*lc;
#pragma unroll
        for (int n = 0; n < 4; ++n) {
            const int gc = colbase + wn*128 + n*32 + lr;
#pragma unroll
            for (int r = 0; r < 16; ++r) {
                int gr = gr0 + (r & 3) + 8*(r >> 2);
                Cpk[(size_t)gr*outStride + gc] = packsplit(acc[m][n][r]);
            }
        }
    }
}

// ---------------- MFMA LSTM cell: gates = P-slices @ W^T; lane-local update ----
// P is PACKED (hi|lo). Wave w owns j-tiles {g*4+w}; lane holds all 4 gates for
// (n = n0 + (lane>>4)*4 + r, k = w*16 + (lane&15)). No LDS, no barriers.
template<int NCH, bool XEP>
__global__ __launch_bounds__(256, 2) void cell_mfma(
        const unsigned int* __restrict__ P,
        const float* __restrict__ convX,
        const float* __restrict__ Wx,
        const short* __restrict__ Wthi, const short* __restrict__ Wtlo,
        const float* __restrict__ bias,
        float* __restrict__ cbuf,
        short* __restrict__ hThi, short* __restrict__ hTlo,
        int tstep) {
    const int t = threadIdx.x;
    const int w = t >> 6, lane = t & 63;
    const int fr = lane & 15, fc = lane >> 4;
    const int b = blockIdx.y;
    const int n0blk = blockIdx.x * 128;
    constexpr int KW = NCH*32;

    bfrag bh[4][NCH], bl[4][NCH];
#pragma unroll
    for (int g = 0; g < 4; ++g)
#pragma unroll
        for (int ch = 0; ch < NCH; ++ch) {
            size_t o = (size_t)((g*4 + w)*16 + fr)*KW + ch*32 + fc*8;
            bh[g][ch] = *(const bfrag*)(Wthi + o);
            bl[g][ch] = *(const bfrag*)(Wtlo + o);
        }
    const int k = w*16 + fr;
    float bs[4], wx0[4], wx1[4];
#pragma unroll
    for (int g = 0; g < 4; ++g) {
        bs[g] = bias[g*64 + k];
        if (XEP) { wx0[g] = Wx[g*64 + k]; wx1[g] = Wx[256 + g*64 + k]; }
    }
    int colb[NCH];
#pragma unroll
    for (int ch = 0; ch < NCH; ++ch)
        colb[ch] = (NCH == 2 || ch < 2) ? (2048 + b*64 + ch*32)
                                        : (b*64 + (ch-2)*32);
    const int cc = lane >> 4;
    const size_t srow = (size_t)(b*64 + k)*NN;

    for (int nt = 0; nt < 8; ++nt) {
        const int n0 = n0blk + nt*16;
        bfrag ah[NCH], al[NCH];
#pragma unroll
        for (int ch = 0; ch < NCH; ++ch) {
            const unsigned int* ap = P + (size_t)(n0 + fr)*PW + colb[ch] + fc*8;
            uint4 u0 = *(const uint4*)ap;
            uint4 u1 = *(const uint4*)(ap + 4);
            unsigned int uu[8] = {u0.x,u0.y,u0.z,u0.w,u1.x,u1.y,u1.z,u1.w};
#pragma unroll
            for (int i = 0; i < 8; ++i) {
                ah[ch][i] = (short)(uu[i] & 0xffffu);
                al[ch][i] = (short)(uu[i] >> 16);
            }
        }
        f32x4 acc[4];
#pragma unroll
        for (int g = 0; g < 4; ++g)
#pragma unroll
            for (int r = 0; r < 4; ++r) acc[g][r] = 0.f;
#pragma unroll
        for (int ch = 0; ch < NCH; ++ch)
#pragma unroll
            for (int g = 0; g < 4; ++g) {
                acc[g] = __builtin_amdgcn_mfma_f32_16x16x32_bf16(ah[ch], bh[g][ch], acc[g], 0, 0, 0);
                acc[g] = __builtin_amdgcn_mfma_f32_16x16x32_bf16(ah[ch], bl[g][ch], acc[g], 0, 0, 0);
                acc[g] = __builtin_amdgcn_mfma_f32_16x16x32_bf16(al[ch], bh[g][ch], acc[g], 0, 0, 0);
            }
        const int nb = n0 + cc*4;
        float4 cold = *(const float4*)(cbuf + srow + nb);
        float xa0[4], xa1[4];
        if (XEP) {
#pragma unroll
            for (int r = 0; r < 4; ++r) {
                float2 cx = *(const float2*)(convX + (size_t)(nb + r)*XC + tstep*64 + b*2);
                xa0[r] = cx.x; xa1[r] = cx.y;
            }
        }
        float cn[4], hv[4];
#pragma unroll
        for (int r = 0; r < 4; ++r) {
            float pg[4];
#pragma unroll
            for (int g = 0; g < 4; ++g) {
                pg[g] = acc[g][r] + bs[g];
                if (XEP) pg[g] += xa0[r]*wx0[g] + xa1[r]*wx1[g];
            }
            float gi = 1.f/(1.f + expf(-pg[0]));
            float gf = 1.f/(1.f + expf(-pg[1]));
            float gg = tanhf(pg[2]);
            float go = 1.f/(1.f + expf(-pg[3]));
            float co = (&cold.x)[r];
            cn[r] = gf*co + gi*gg;
            hv[r] = go * tanhf(cn[r]);
        }
        *(float4*)(cbuf + srow + nb) = make_float4(cn[0], cn[1], cn[2], cn[3]);
        short hh[4], hl[4];
#pragma unroll
        for (int r = 0; r < 4; ++r) {
            hh[r] = f2bf(hv[r]);
            hl[r] = f2bf(hv[r] - bf2f(hh[r]));
        }
        *(short4*)(hThi + srow + nb) = make_short4(hh[0], hh[1], hh[2], hh[3]);
        *(short4*)(hTlo + srow + nb) = make_short4(hl[0], hl[1], hl[2], hl[3]);
    }
}

// ---------------- out = h2 @ Wp + bp -> [B,HOR,N,1] ----------------
__global__ __launch_bounds__(256) void proj_T(const short* __restrict__ h2hi,
        const short* __restrict__ h2lo, const float* __restrict__ Wp,
        const float* __restrict__ bp, float* __restrict__ out) {
    __shared__ float sW[HH*HOR];
    __shared__ float sb[HOR];
    for (int i = threadIdx.x; i < HH*HOR; i += 256) sW[i] = Wp[i];
    if (threadIdx.x < HOR) sb[threadIdx.x] = bp[threadIdx.x];
    __syncthreads();
    int idx = blockIdx.x*256 + threadIdx.x;    // b*2048 + n
    int b = idx >> 11, n = idx & (NN-1);
    float acc[HOR];
#pragma unroll
    for (int j = 0; j < HOR; ++j) acc[j] = sb[j];
    for (int k = 0; k < HH; ++k) {
        size_t row = (size_t)(b*64 + k)*NN + n;
        float h = bf2f(h2hi[row]) + bf2f(h2lo[row]);
#pragma unroll
        for (int j = 0; j < HOR; ++j) acc[j] = fmaf(h, sW[k*HOR + j], acc[j]);
    }
#pragma unroll
    for (int j = 0; j < HOR; ++j)
        out[(size_t)(b*HOR + j)*NN + n] = acc[j];
}

extern "C" void kernel_launch(void* const* d_in, const int* in_sizes, int n_in,
                              void* d_out, int out_size, void* d_ws, size_t ws_size,
                              hipStream_t stream) {
    const float* x  = (const float*)d_in[0];
    const float* E  = (const float*)d_in[1];
    const float* W1 = (const float*)d_in[2];
    const float* b1 = (const float*)d_in[3];
    const float* W2 = (const float*)d_in[4];
    const float* b2 = (const float*)d_in[5];
    const float* Wp = (const float*)d_in[6];
    const float* bp = (const float*)d_in[7];
    float* out = (float*)d_out;

    char* base = (char*)d_ws;
    short* Ahi    = (short*)base; base += (size_t)NN*NN*2;
    short* Alo    = (short*)base; base += (size_t)NN*NN*2;
    float* convX  = (float*)base; base += (size_t)NN*XC*4;
    unsigned int* P = (unsigned int*)base; base += (size_t)NN*PW*4;
    short* hAllhi = (short*)base; base += (size_t)2*NN*NN*2;
    short* hAlllo = (short*)base; base += (size_t)2*NN*NN*2;
    float* cs1    = (float*)base; base += (size_t)NN*NN*4;
    float* cs2    = (float*)base; base += (size_t)NN*NN*4;
    short* Wt2hi  = (short*)base; base += 256*128*2;
    short* Wt2lo  = (short*)base; base += 256*128*2;
    short* Wt1hi  = (short*)base; base += 256*64*2;
    short* Wt1lo  = (short*)base; base += 256*64*2;
    // XallT aliases P (consumed by convX GEMM before P is zeroed)
    short* XThi = (short*)P;
    short* XTlo = XThi + (size_t)XC*NN;
    short* h1Thi = hAllhi + (size_t)NN*NN;   // rows 2048.. = h1T
    short* h1Tlo = hAlllo + (size_t)NN*NN;

    hipMemsetAsync(cs1, 0, (size_t)NN*NN*4, stream);
    hipMemsetAsync(cs2, 0, (size_t)NN*NN*4, stream);

    compute_A_kernel<<<NN, 256, 0, stream>>>(E, Ahi, Alo);
    wsplit_T<<<(256*128 + 255)/256, 256, 0, stream>>>(W2, 0, 128, Wt2hi, Wt2lo);
    wsplit_T<<<(256*64 + 255)/256, 256, 0, stream>>>(W1, 2, 64, Wt1hi, Wt1lo);
    scatter_xall<<<(XC*NN)/256, 256, 0, stream>>>(x, XThi, XTlo);
    // convX = A @ Xall (once, all timesteps, f32)
    gc3_gemm<<<dim3(XC/128, NN/64), 256, 0, stream>>>(Ahi, Alo, XThi, XTlo, convX, XC);
    // XT region dead -> zero packed P for first-step reads (packed 0 == 0.0f)
    hipMemsetAsync(P, 0, (size_t)NN*PW*4, stream);

    // cell1(0): reads P1=0 + convX(t=0) -> h1T(0)
    cell_mfma<2, true><<<dim3(NN/128, BB), 256, 0, stream>>>(
        P, convX, W1, Wt1hi, Wt1lo, b1, cs1, h1Thi, h1Tlo, 0);
    // P1(0) = A @ h1(0)  (packed)
    gc32_gemm<<<dim3(NN/256, NN/128), 256, 0, stream>>>(
        Ahi, Alo, h1Thi, h1Tlo, P + 2048, PW);

    for (int t = 0; t < TT; ++t) {
        // cell2(t): reads P1(t), P2(t-1) -> h2T(t)
        cell_mfma<4, false><<<dim3(NN/128, BB), 256, 0, stream>>>(
            P, nullptr, nullptr, Wt2hi, Wt2lo, b2, cs2, hAllhi, hAlllo, 0);
        if (t < TT-1) {
            // cell1(t+1): reads P1(t), convX(t+1) -> h1T(t+1)
            cell_mfma<2, true><<<dim3(NN/128, BB), 256, 0, stream>>>(
                P, convX, W1, Wt1hi, Wt1lo, b1, cs1, h1Thi, h1Tlo, t+1);
            // merged GEMM: [P2(t) | P1(t+1)] = A @ [h2(t) | h1(t+1)]  (packed)
            gc32_gemm<<<dim3(PW/256, NN/128), 256, 0, stream>>>(
                Ahi, Alo, hAllhi, hAlllo, P, PW);
        }
    }
    proj_T<<<(BB*NN)/256, 256, 0, stream>>>(hAllhi, hAlllo, Wp, bp, out);
}

// Round 6
// 4148.469 us; speedup vs baseline: 1.3132x; 1.3132x over previous
//
#include <hip/hip_runtime.h>
#include <hip/hip_bf16.h>
#include <cstddef>
#include <cstdint>

#define NN   2048
#define BB   32
#define TT   24
#define CIN  2
#define HH   64
#define EMBD 16
#define HOR  12
#define XC   (TT*BB*CIN)   // 1536 cols of precomputed A@x
#define PW   4096          // P row width: cols [0,2048)=P2, [2048,4096)=P1
#define KC   6144          // concat K: [hi | hi | lo] x 2048
#define NT   96            // K-tiles of 64

using bfrag  = __attribute__((ext_vector_type(8))) short;   // 8 bf16 = 4 VGPR
using f32x4  = __attribute__((ext_vector_type(4))) float;

static __device__ __forceinline__ short f2bf(float f) {
    __hip_bfloat16 h = __float2bfloat16(f);
    return *reinterpret_cast<short*>(&h);
}
static __device__ __forceinline__ float bf2f(short s) {
    __hip_bfloat16 h;
    *reinterpret_cast<short*>(&h) = s;
    return __bfloat162float(h);
}
static __device__ __forceinline__ unsigned int packsplit(float v) {
    short hb = f2bf(v);
    short lb = f2bf(v - bf2f(hb));
    return (unsigned int)(unsigned short)hb | ((unsigned int)(unsigned short)lb << 16);
}

#define AS1 __attribute__((address_space(1)))
#define AS3 __attribute__((address_space(3)))
static __device__ __forceinline__ void gload16(const short* g, short* l) {
    __builtin_amdgcn_global_load_lds((const AS1 void*)g, (AS3 void*)l, 16, 0, 0);
}

// ---------- A = softmax(relu(E E^T)) -> A2 rows [Ahi | Ahi | Alo] (6144) ------
__global__ __launch_bounds__(256) void compute_A_kernel(const float* __restrict__ E,
                                                        short* __restrict__ A2) {
    __shared__ float srow[NN];
    __shared__ float sred[256];
    int row = blockIdx.x;
    float er[EMBD];
#pragma unroll
    for (int k = 0; k < EMBD; ++k) er[k] = E[row*EMBD + k];
    float lmax = -1e30f;
    for (int j = threadIdx.x; j < NN; j += 256) {
        const float* ej = E + j*EMBD;
        float d = 0.f;
#pragma unroll
        for (int k = 0; k < EMBD; ++k) d = fmaf(er[k], ej[k], d);
        d = fmaxf(d, 0.f);
        srow[j] = d;
        lmax = fmaxf(lmax, d);
    }
    sred[threadIdx.x] = lmax;
    __syncthreads();
    for (int s = 128; s > 0; s >>= 1) {
        if (threadIdx.x < s) sred[threadIdx.x] = fmaxf(sred[threadIdx.x], sred[threadIdx.x+s]);
        __syncthreads();
    }
    float rmax = sred[0];
    __syncthreads();
    float lsum = 0.f;
    for (int j = threadIdx.x; j < NN; j += 256) {
        float e = expf(srow[j] - rmax);
        srow[j] = e;
        lsum += e;
    }
    sred[threadIdx.x] = lsum;
    __syncthreads();
    for (int s = 128; s > 0; s >>= 1) {
        if (threadIdx.x < s) sred[threadIdx.x] += sred[threadIdx.x+s];
        __syncthreads();
    }
    float rinv = 1.f / sred[0];
    for (int j = threadIdx.x; j < NN; j += 256) {
        float v = srow[j] * rinv;
        short h = f2bf(v);
        short l = f2bf(v - bf2f(h));
        size_t base = (size_t)row*KC + j;
        A2[base]        = h;
        A2[base + 2048] = h;
        A2[base + 4096] = l;
    }
}

// ---------------- build XallT hi/lo: [col=(t*32+b)*2+c][n] ----------------
__global__ void scatter_xall(const float* __restrict__ x,
                             short* __restrict__ hi, short* __restrict__ lo) {
    int idx = blockIdx.x*256 + threadIdx.x;     // col*2048 + n
    int n = idx & (NN-1);
    int col = idx >> 11;
    int c = col & 1, b = (col >> 1) & 31, t = col >> 6;
    float v = x[(size_t)(((size_t)b*TT + t)*NN + n)*CIN + c];
    short h = f2bf(v);
    size_t o = (size_t)col*NN + n;
    hi[o] = h;
    lo[o] = f2bf(v - bf2f(h));
}

// ---------------- W^T split: Wt[j][c] = split(W[rowoff+c][j]) ----------------
__global__ void wsplit_T(const float* __restrict__ W, int rowoff, int Kd,
                         short* __restrict__ hi, short* __restrict__ lo) {
    int id = blockIdx.x*256 + threadIdx.x;      // j*Kd + c
    if (id >= 256*Kd) return;
    int j = id / Kd, c = id - j*Kd;
    float v = W[(size_t)(rowoff + c)*256 + j];
    short h = f2bf(v);
    hi[id] = h;
    lo[id] = f2bf(v - bf2f(h));
}

// ---------------- convX GEMM: f32 out (proven kernel; A strided) --------------
__global__ __launch_bounds__(256, 3) void gc3_gemm(
        const short* __restrict__ Ahi, const short* __restrict__ Alo,
        const short* __restrict__ Bhi, const short* __restrict__ Blo,
        float* __restrict__ Cout, int outStride, int astr) {
    __shared__ short As[12288];
    short* AsHi = As;
    short* AsLo = As + 2048;
    short* BsHi = As + 4096;
    short* BsLo = As + 8192;
    const int t = threadIdx.x;
    const int w = t >> 6, lane = t & 63;
    const int wm = w >> 1, wn = w & 1;
    const int fr = lane & 15, fc = lane >> 4;
    const int rowbase = blockIdx.y * 64;
    const int colbase = blockIdx.x * 128;

    const int rp = t >> 3, ql = t & 7;
    const int qs = ql ^ (rp & 7);
    const int srow = rp*2 + (qs >> 2);
    const int sch  = (qs & 3) * 8;
    const short* aHiS = Ahi + (size_t)(rowbase + srow)*astr + sch;
    const short* aLoS = Alo + (size_t)(rowbase + srow)*astr + sch;
    const short* bHiS = Bhi + (size_t)(colbase + srow)*NN + sch;
    const short* bLoS = Blo + (size_t)(colbase + srow)*NN + sch;
    const size_t bHalf = (size_t)64*NN;

    short* aHiD  = AsHi + t*8;
    short* aLoD  = AsLo + t*8;
    short* bHiD0 = BsHi + t*8;
    short* bHiD1 = BsHi + 2048 + t*8;
    short* bLoD0 = BsLo + t*8;
    short* bLoD1 = BsLo + 2048 + t*8;

    auto ldsoff = [](int row, int f) {
        int rr = row >> 1;
        int q = (((row & 1) << 2) | f) ^ (rr & 7);
        return rr*64 + q*8;
    };
    int aoff[2], boff[4];
#pragma unroll
    for (int m = 0; m < 2; ++m) aoff[m] = ldsoff(wm*32 + m*16 + fr, fc);
#pragma unroll
    for (int n = 0; n < 4; ++n) boff[n] = ldsoff(wn*64 + n*16 + fr, fc);

    f32x4 acc[2][4];
#pragma unroll
    for (int m = 0; m < 2; ++m)
#pragma unroll
        for (int n = 0; n < 4; ++n)
#pragma unroll
            for (int r = 0; r < 4; ++r) acc[m][n][r] = 0.f;

    for (int k0 = 0; k0 < NN; k0 += 32) {
        gload16(aHiS, aHiD);
        gload16(aLoS, aLoD);
        gload16(bHiS, bHiD0);
        gload16(bHiS + bHalf, bHiD1);
        gload16(bLoS, bLoD0);
        gload16(bLoS + bHalf, bLoD1);
        aHiS += 32; aLoS += 32; bHiS += 32; bLoS += 32;
        __syncthreads();
        bfrag ah[2], al[2], bh[4], bl[4];
#pragma unroll
        for (int m = 0; m < 2; ++m) {
            ah[m] = *(const bfrag*)(AsHi + aoff[m]);
            al[m] = *(const bfrag*)(AsLo + aoff[m]);
        }
#pragma unroll
        for (int n = 0; n < 4; ++n) {
            bh[n] = *(const bfrag*)(BsHi + boff[n]);
            bl[n] = *(const bfrag*)(BsLo + boff[n]);
        }
#pragma unroll
        for (int m = 0; m < 2; ++m)
#pragma unroll
            for (int n = 0; n < 4; ++n) {
                acc[m][n] = __builtin_amdgcn_mfma_f32_16x16x32_bf16(ah[m], bh[n], acc[m][n], 0, 0, 0);
                acc[m][n] = __builtin_amdgcn_mfma_f32_16x16x32_bf16(ah[m], bl[n], acc[m][n], 0, 0, 0);
                acc[m][n] = __builtin_amdgcn_mfma_f32_16x16x32_bf16(al[m], bh[n], acc[m][n], 0, 0, 0);
            }
        __syncthreads();
    }
#pragma unroll
    for (int m = 0; m < 2; ++m) {
        const int gr = rowbase + wm*32 + m*16 + fc*4;
#pragma unroll
        for (int n = 0; n < 4; ++n) {
            const int gc = colbase + wn*64 + n*16 + fr;
#pragma unroll
            for (int r = 0; r < 4; ++r)
                Cout[(size_t)(gr + r)*outStride + gc] = acc[m][n][r];
        }
    }
}

// ------- recurrent GEMM: plain bf16, K=6144, 8-phase-style counted pipeline ---
// C[2048][PW] packed = A2[2048][6144] @ B2[4096][6144]^T
// 128x256 tile, 8 waves (2Mx4N), BK=64, 3-deep LDS (144KB), vmcnt(6) counted.
__global__ __launch_bounds__(512, 2) void gemm8p(
        const short* __restrict__ A2, const short* __restrict__ B2,
        unsigned int* __restrict__ Cpk, int colstart) {
    __shared__ short lds[3*24576];
    const int tid = threadIdx.x;
    const int w = tid >> 6, lane = tid & 63;
    const int wm = w >> 2, wn = w & 3;
    const int fr = lane & 15, fc = lane >> 4;
    // bijective XCD swizzle (grid counts divisible by 8)
    const int gx = gridDim.x;
    const int nwg = gx * gridDim.y;
    const int fid = blockIdx.y * gx + blockIdx.x;
    const int swz = (fid & 7) * (nwg >> 3) + (fid >> 3);
    const int rowbase = (swz / gx) * 128;
    const int colbase = colstart + (swz % gx) * 256;

    // staging: thread -> one 16B chunk per 8KB sweep; pre-swizzled source
    const int srl = tid >> 3;                    // row within 64-row sweep
    const int sck = (tid & 7) ^ (srl & 7);       // source chunk
    const short* aS0 = A2 + (size_t)(rowbase + srl)*KC + sck*8;
    const short* aS1 = A2 + (size_t)(rowbase + 64 + srl)*KC + sck*8;
    const short* bS0 = B2 + (size_t)(colbase + srl)*KC + sck*8;
    const short* bS1 = B2 + (size_t)(colbase + 64 + srl)*KC + sck*8;
    const short* bS2 = B2 + (size_t)(colbase + 128 + srl)*KC + sck*8;
    const short* bS3 = B2 + (size_t)(colbase + 192 + srl)*KC + sck*8;

    // swizzled fragment read offsets (shorts)
    auto sw = [](int row, int chunk) {
        int c2 = chunk ^ (row & 7);
        return row*64 + c2*8;
    };
    int aoff[4][2], boff[4][2];
#pragma unroll
    for (int m = 0; m < 4; ++m)
#pragma unroll
        for (int kk = 0; kk < 2; ++kk)
            aoff[m][kk] = sw(wm*64 + m*16 + fr, kk*4 + fc);
#pragma unroll
    for (int n = 0; n < 4; ++n)
#pragma unroll
        for (int kk = 0; kk < 2; ++kk)
            boff[n][kk] = 8192 + sw(wn*64 + n*16 + fr, kk*4 + fc);

    bfrag a[4][2], b[4][2];
    f32x4 acc[4][4];
#pragma unroll
    for (int m = 0; m < 4; ++m)
#pragma unroll
        for (int n = 0; n < 4; ++n)
#pragma unroll
            for (int r = 0; r < 4; ++r) acc[m][n][r] = 0.f;

    auto MFMA8 = [&](int m0, int n0) {
#pragma unroll
        for (int dm = 0; dm < 2; ++dm)
#pragma unroll
            for (int dn = 0; dn < 2; ++dn)
#pragma unroll
                for (int kk = 0; kk < 2; ++kk)
                    acc[m0+dm][n0+dn] = __builtin_amdgcn_mfma_f32_16x16x32_bf16(
                        a[m0+dm][kk], b[n0+dn][kk], acc[m0+dm][n0+dn], 0, 0, 0);
    };

    short* bC = lds;             // current compute buffer
    short* bN = lds + 24576;     // next (staged)
    short* bP = lds + 49152;     // prefetch dest (t+2)

    // prologue: stage tiles 0 and 1
    gload16(aS0, bC + tid*8);            gload16(aS1, bC + 4096 + tid*8);
    gload16(bS0, bC + 8192 + tid*8);     gload16(bS1, bC + 12288 + tid*8);
    gload16(bS2, bC + 16384 + tid*8);    gload16(bS3, bC + 20480 + tid*8);
    gload16(aS0 + 64, bN + tid*8);          gload16(aS1 + 64, bN + 4096 + tid*8);
    gload16(bS0 + 64, bN + 8192 + tid*8);   gload16(bS1 + 64, bN + 12288 + tid*8);
    gload16(bS2 + 64, bN + 16384 + tid*8);  gload16(bS3 + 64, bN + 20480 + tid*8);

    for (int t = 0; t < NT; ++t) {
        if (t < NT-1) { asm volatile("s_waitcnt vmcnt(6)" ::: "memory"); }
        else          { asm volatile("s_waitcnt vmcnt(0)" ::: "memory"); }
        __builtin_amdgcn_s_barrier();
        __builtin_amdgcn_sched_barrier(0);
        const bool pf = (t + 2 < NT);
        const int toff = (t + 2) * 64;
        // ---- phase 0: a01,b01 reads; A prefetch; MFMA m01 x n01 ----
#pragma unroll
        for (int kk = 0; kk < 2; ++kk) {
            a[0][kk] = *(const bfrag*)(bC + aoff[0][kk]);
            a[1][kk] = *(const bfrag*)(bC + aoff[1][kk]);
            b[0][kk] = *(const bfrag*)(bC + boff[0][kk]);
            b[1][kk] = *(const bfrag*)(bC + boff[1][kk]);
        }
        if (pf) {
            gload16(aS0 + toff, bP + tid*8);
            gload16(aS1 + toff, bP + 4096 + tid*8);
        }
        __builtin_amdgcn_s_barrier();
        __builtin_amdgcn_sched_barrier(0);
        __builtin_amdgcn_s_setprio(1);
        MFMA8(0, 0);
        __builtin_amdgcn_s_setprio(0);
        __builtin_amdgcn_s_barrier();
        __builtin_amdgcn_sched_barrier(0);
        // ---- phase 1: b23 reads; B prefetch 0,1; MFMA m01 x n23 ----
#pragma unroll
        for (int kk = 0; kk < 2; ++kk) {
            b[2][kk] = *(const bfrag*)(bC + boff[2][kk]);
            b[3][kk] = *(const bfrag*)(bC + boff[3][kk]);
        }
        if (pf) {
            gload16(bS0 + toff, bP + 8192 + tid*8);
            gload16(bS1 + toff, bP + 12288 + tid*8);
        }
        __builtin_amdgcn_s_barrier();
        __builtin_amdgcn_sched_barrier(0);
        __builtin_amdgcn_s_setprio(1);
        MFMA8(0, 2);
        __builtin_amdgcn_s_setprio(0);
        __builtin_amdgcn_s_barrier();
        __builtin_amdgcn_sched_barrier(0);
        // ---- phase 2: a23 reads; B prefetch 2,3; MFMA m23 x n01 ----
#pragma unroll
        for (int kk = 0; kk < 2; ++kk) {
            a[2][kk] = *(const bfrag*)(bC + aoff[2][kk]);
            a[3][kk] = *(const bfrag*)(bC + aoff[3][kk]);
        }
        if (pf) {
            gload16(bS2 + toff, bP + 16384 + tid*8);
            gload16(bS3 + toff, bP + 20480 + tid*8);
        }
        __builtin_amdgcn_s_barrier();
        __builtin_amdgcn_sched_barrier(0);
        __builtin_amdgcn_s_setprio(1);
        MFMA8(2, 0);
        __builtin_amdgcn_s_setprio(0);
        __builtin_amdgcn_s_barrier();
        __builtin_amdgcn_sched_barrier(0);
        // ---- phase 3: MFMA m23 x n23 ----
        __builtin_amdgcn_s_setprio(1);
        MFMA8(2, 2);
        __builtin_amdgcn_s_setprio(0);
        // rotate buffers
        short* tmp = bC; bC = bN; bN = bP; bP = tmp;
    }
    // epilogue: packed split store. C/D: col = lane&15, row = (lane>>4)*4 + r
#pragma unroll
    for (int m = 0; m < 4; ++m) {
        const int gr0 = rowbase + wm*64 + m*16 + fc*4;
#pragma unroll
        for (int n = 0; n < 4; ++n) {
            const int gc = colbase + wn*64 + n*16 + fr;
#pragma unroll
            for (int r = 0; r < 4; ++r)
                Cpk[(size_t)(gr0 + r)*PW + gc] = packsplit(acc[m][n][r]);
        }
    }
}

// ---------------- MFMA LSTM cell: gates = P-slices @ W^T; lane-local update ----
// P packed (hi|lo). h written to B2 rows: [n]=hi, [2048+n]=lo, [4096+n]=hi.
template<int NCH, bool XEP>
__global__ __launch_bounds__(256, 2) void cell_mfma(
        const unsigned int* __restrict__ P,
        const float* __restrict__ convX,
        const float* __restrict__ Wx,
        const short* __restrict__ Wthi, const short* __restrict__ Wtlo,
        const float* __restrict__ bias,
        float* __restrict__ cbuf,
        short* __restrict__ hout,     // B2 + rowoff*KC
        int tstep) {
    const int t = threadIdx.x;
    const int w = t >> 6, lane = t & 63;
    const int fr = lane & 15, fc = lane >> 4;
    const int b = blockIdx.y;
    const int n0blk = blockIdx.x * 128;
    constexpr int KW = NCH*32;

    bfrag bh[4][NCH], bl[4][NCH];
#pragma unroll
    for (int g = 0; g < 4; ++g)
#pragma unroll
        for (int ch = 0; ch < NCH; ++ch) {
            size_t o = (size_t)((g*4 + w)*16 + fr)*KW + ch*32 + fc*8;
            bh[g][ch] = *(const bfrag*)(Wthi + o);
            bl[g][ch] = *(const bfrag*)(Wtlo + o);
        }
    const int k = w*16 + fr;
    float bs[4], wx0[4], wx1[4];
#pragma unroll
    for (int g = 0; g < 4; ++g) {
        bs[g] = bias[g*64 + k];
        if (XEP) { wx0[g] = Wx[g*64 + k]; wx1[g] = Wx[256 + g*64 + k]; }
    }
    int colb[NCH];
#pragma unroll
    for (int ch = 0; ch < NCH; ++ch)
        colb[ch] = (NCH == 2 || ch < 2) ? (2048 + b*64 + ch*32)
                                        : (b*64 + (ch-2)*32);
    const int cc = lane >> 4;
    const size_t crow = (size_t)(b*64 + k)*NN;
    const size_t hrow = (size_t)(b*64 + k)*KC;

    for (int nt = 0; nt < 8; ++nt) {
        const int n0 = n0blk + nt*16;
        bfrag ah[NCH], al[NCH];
#pragma unroll
        for (int ch = 0; ch < NCH; ++ch) {
            const unsigned int* ap = P + (size_t)(n0 + fr)*PW + colb[ch] + fc*8;
            uint4 u0 = *(const uint4*)ap;
            uint4 u1 = *(const uint4*)(ap + 4);
            unsigned int uu[8] = {u0.x,u0.y,u0.z,u0.w,u1.x,u1.y,u1.z,u1.w};
#pragma unroll
            for (int i = 0; i < 8; ++i) {
                ah[ch][i] = (short)(uu[i] & 0xffffu);
                al[ch][i] = (short)(uu[i] >> 16);
            }
        }
        f32x4 acc[4];
#pragma unroll
        for (int g = 0; g < 4; ++g)
#pragma unroll
            for (int r = 0; r < 4; ++r) acc[g][r] = 0.f;
#pragma unroll
        for (int ch = 0; ch < NCH; ++ch)
#pragma unroll
            for (int g = 0; g < 4; ++g) {
                acc[g] = __builtin_amdgcn_mfma_f32_16x16x32_bf16(ah[ch], bh[g][ch], acc[g], 0, 0, 0);
                acc[g] = __builtin_amdgcn_mfma_f32_16x16x32_bf16(ah[ch], bl[g][ch], acc[g], 0, 0, 0);
                acc[g] = __builtin_amdgcn_mfma_f32_16x16x32_bf16(al[ch], bh[g][ch], acc[g], 0, 0, 0);
            }
        const int nb = n0 + cc*4;
        float4 cold = *(const float4*)(cbuf + crow + nb);
        float xa0[4], xa1[4];
        if (XEP) {
#pragma unroll
            for (int r = 0; r < 4; ++r) {
                float2 cx = *(const float2*)(convX + (size_t)(nb + r)*XC + tstep*64 + b*2);
                xa0[r] = cx.x; xa1[r] = cx.y;
            }
        }
        float cn[4], hv[4];
#pragma unroll
        for (int r = 0; r < 4; ++r) {
            float pg[4];
#pragma unroll
            for (int g = 0; g < 4; ++g) {
                pg[g] = acc[g][r] + bs[g];
                if (XEP) pg[g] += xa0[r]*wx0[g] + xa1[r]*wx1[g];
            }
            float gi = 1.f/(1.f + expf(-pg[0]));
            float gf = 1.f/(1.f + expf(-pg[1]));
            float gg = tanhf(pg[2]);
            float go = 1.f/(1.f + expf(-pg[3]));
            float co = (&cold.x)[r];
            cn[r] = gf*co + gi*gg;
            hv[r] = go * tanhf(cn[r]);
        }
        *(float4*)(cbuf + crow + nb) = make_float4(cn[0], cn[1], cn[2], cn[3]);
        short hh[4], hl[4];
#pragma unroll
        for (int r = 0; r < 4; ++r) {
            hh[r] = f2bf(hv[r]);
            hl[r] = f2bf(hv[r] - bf2f(hh[r]));
        }
        short4 h4 = make_short4(hh[0], hh[1], hh[2], hh[3]);
        short4 l4 = make_short4(hl[0], hl[1], hl[2], hl[3]);
        *(short4*)(hout + hrow + nb)        = h4;
        *(short4*)(hout + hrow + 2048 + nb) = l4;
        *(short4*)(hout + hrow + 4096 + nb) = h4;
    }
}

// ---------------- out = h2 @ Wp + bp -> [B,HOR,N,1] ----------------
__global__ __launch_bounds__(256) void proj_T(const short* __restrict__ B2,
        const float* __restrict__ Wp, const float* __restrict__ bp,
        float* __restrict__ out) {
    __shared__ float sW[HH*HOR];
    __shared__ float sb[HOR];
    for (int i = threadIdx.x; i < HH*HOR; i += 256) sW[i] = Wp[i];
    if (threadIdx.x < HOR) sb[threadIdx.x] = bp[threadIdx.x];
    __syncthreads();
    int idx = blockIdx.x*256 + threadIdx.x;    // b*2048 + n
    int b = idx >> 11, n = idx & (NN-1);
    float acc[HOR];
#pragma unroll
    for (int j = 0; j < HOR; ++j) acc[j] = sb[j];
    for (int k = 0; k < HH; ++k) {
        size_t row = (size_t)(b*64 + k)*KC + n;
        float h = bf2f(B2[row]) + bf2f(B2[row + 2048]);
#pragma unroll
        for (int j = 0; j < HOR; ++j) acc[j] = fmaf(h, sW[k*HOR + j], acc[j]);
    }
#pragma unroll
    for (int j = 0; j < HOR; ++j)
        out[(size_t)(b*HOR + j)*NN + n] = acc[j];
}

extern "C" void kernel_launch(void* const* d_in, const int* in_sizes, int n_in,
                              void* d_out, int out_size, void* d_ws, size_t ws_size,
                              hipStream_t stream) {
    const float* x  = (const float*)d_in[0];
    const float* E  = (const float*)d_in[1];
    const float* W1 = (const float*)d_in[2];
    const float* b1 = (const float*)d_in[3];
    const float* W2 = (const float*)d_in[4];
    const float* b2 = (const float*)d_in[5];
    const float* Wp = (const float*)d_in[6];
    const float* bp = (const float*)d_in[7];
    float* out = (float*)d_out;

    char* base = (char*)d_ws;
    short* A2     = (short*)base; base += (size_t)NN*KC*2;      // 25.2M
    float* convX  = (float*)base; base += (size_t)NN*XC*4;      // 12.6M
    unsigned int* P = (unsigned int*)base; base += (size_t)NN*PW*4;  // 33.6M
    short* B2     = (short*)base; base += (size_t)PW*KC*2;      // 50.3M
    float* cs1    = (float*)base; base += (size_t)NN*NN*4;      // 16.8M
    float* cs2    = (float*)base; base += (size_t)NN*NN*4;      // 16.8M
    short* Wt2hi  = (short*)base; base += 256*128*2;
    short* Wt2lo  = (short*)base; base += 256*128*2;
    short* Wt1hi  = (short*)base; base += 256*64*2;
    short* Wt1lo  = (short*)base; base += 256*64*2;
    // XallT aliases P (consumed by convX GEMM before P is zeroed)
    short* XThi = (short*)P;
    short* XTlo = XThi + (size_t)XC*NN;
    short* h2out = B2;                        // rows [0,2048)  = h2
    short* h1out = B2 + (size_t)NN*KC;        // rows [2048,4096) = h1

    hipMemsetAsync(cs1, 0, (size_t)NN*NN*4, stream);
    hipMemsetAsync(cs2, 0, (size_t)NN*NN*4, stream);

    compute_A_kernel<<<NN, 256, 0, stream>>>(E, A2);
    wsplit_T<<<(256*128 + 255)/256, 256, 0, stream>>>(W2, 0, 128, Wt2hi, Wt2lo);
    wsplit_T<<<(256*64 + 255)/256, 256, 0, stream>>>(W1, 2, 64, Wt1hi, Wt1lo);
    scatter_xall<<<(XC*NN)/256, 256, 0, stream>>>(x, XThi, XTlo);
    // convX = A @ Xall (once, all timesteps, f32)
    gc3_gemm<<<dim3(XC/128, NN/64), 256, 0, stream>>>(
        A2, A2 + 4096, XThi, XTlo, convX, XC, KC);
    // XT region dead -> zero packed P for first-step reads
    hipMemsetAsync(P, 0, (size_t)NN*PW*4, stream);

    // cell1(0): reads P1=0 + convX(t=0) -> h1 rows of B2
    cell_mfma<2, true><<<dim3(NN/128, BB), 256, 0, stream>>>(
        P, convX, W1, Wt1hi, Wt1lo, b1, cs1, h1out, 0);
    // P1(0) = A @ h1(0)  (cols [2048,4096) only)
    gemm8p<<<dim3(8, 16), 512, 0, stream>>>(A2, B2, P, 2048);

    for (int t = 0; t < TT; ++t) {
        // cell2(t): reads P1(t), P2(t-1) -> h2 rows of B2
        cell_mfma<4, false><<<dim3(NN/128, BB), 256, 0, stream>>>(
            P, nullptr, nullptr, Wt2hi, Wt2lo, b2, cs2, h2out, 0);
        if (t < TT-1) {
            // cell1(t+1): reads P1(t), convX(t+1) -> h1 rows of B2
            cell_mfma<2, true><<<dim3(NN/128, BB), 256, 0, stream>>>(
                P, convX, W1, Wt1hi, Wt1lo, b1, cs1, h1out, t+1);
            // merged GEMM: [P2(t) | P1(t+1)] = A @ [h2(t) | h1(t+1)]
            gemm8p<<<dim3(16, 16), 512, 0, stream>>>(A2, B2, P, 0);
        }
    }
    proj_T<<<(BB*NN)/256, 256, 0, stream>>>(B2, Wp, bp, out);
}

// Round 7
// 4005.520 us; speedup vs baseline: 1.3600x; 1.0357x over previous
//
#include <hip/hip_runtime.h>
#include <hip/hip_bf16.h>
#include <cstddef>
#include <cstdint>

#define NN   2048
#define BB   32
#define TT   24
#define CIN  2
#define HH   64
#define EMBD 16
#define HOR  12
#define XC   (TT*BB*CIN)   // 1536 cols of precomputed A@x
#define PW   4096          // P row width: cols [0,2048)=P2, [2048,4096)=P1
#define KC   6144          // concat K: [hi | hi | lo] x 2048
#define NT   96            // K-tiles of 64

using bfrag  = __attribute__((ext_vector_type(8))) short;   // 8 bf16 = 4 VGPR
using f32x4  = __attribute__((ext_vector_type(4))) float;

static __device__ __forceinline__ short f2bf(float f) {
    __hip_bfloat16 h = __float2bfloat16(f);
    return *reinterpret_cast<short*>(&h);
}
static __device__ __forceinline__ float bf2f(short s) {
    __hip_bfloat16 h;
    *reinterpret_cast<short*>(&h) = s;
    return __bfloat162float(h);
}
static __device__ __forceinline__ unsigned int packsplit(float v) {
    short hb = f2bf(v);
    short lb = f2bf(v - bf2f(hb));
    return (unsigned int)(unsigned short)hb | ((unsigned int)(unsigned short)lb << 16);
}

#define AS1 __attribute__((address_space(1)))
#define AS3 __attribute__((address_space(3)))
static __device__ __forceinline__ void gload16(const short* g, short* l) {
    __builtin_amdgcn_global_load_lds((const AS1 void*)g, (AS3 void*)l, 16, 0, 0);
}

// ---------- A = softmax(relu(E E^T)) -> A2 rows [Ahi | Ahi | Alo] (6144) ------
__global__ __launch_bounds__(256) void compute_A_kernel(const float* __restrict__ E,
                                                        short* __restrict__ A2) {
    __shared__ float srow[NN];
    __shared__ float sred[256];
    int row = blockIdx.x;
    float er[EMBD];
#pragma unroll
    for (int k = 0; k < EMBD; ++k) er[k] = E[row*EMBD + k];
    float lmax = -1e30f;
    for (int j = threadIdx.x; j < NN; j += 256) {
        const float* ej = E + j*EMBD;
        float d = 0.f;
#pragma unroll
        for (int k = 0; k < EMBD; ++k) d = fmaf(er[k], ej[k], d);
        d = fmaxf(d, 0.f);
        srow[j] = d;
        lmax = fmaxf(lmax, d);
    }
    sred[threadIdx.x] = lmax;
    __syncthreads();
    for (int s = 128; s > 0; s >>= 1) {
        if (threadIdx.x < s) sred[threadIdx.x] = fmaxf(sred[threadIdx.x], sred[threadIdx.x+s]);
        __syncthreads();
    }
    float rmax = sred[0];
    __syncthreads();
    float lsum = 0.f;
    for (int j = threadIdx.x; j < NN; j += 256) {
        float e = expf(srow[j] - rmax);
        srow[j] = e;
        lsum += e;
    }
    sred[threadIdx.x] = lsum;
    __syncthreads();
    for (int s = 128; s > 0; s >>= 1) {
        if (threadIdx.x < s) sred[threadIdx.x] += sred[threadIdx.x+s];
        __syncthreads();
    }
    float rinv = 1.f / sred[0];
    for (int j = threadIdx.x; j < NN; j += 256) {
        float v = srow[j] * rinv;
        short h = f2bf(v);
        short l = f2bf(v - bf2f(h));
        size_t base = (size_t)row*KC + j;
        A2[base]        = h;
        A2[base + 2048] = h;
        A2[base + 4096] = l;
    }
}

// ---------------- build XallT hi/lo: [col=(t*32+b)*2+c][n] ----------------
__global__ void scatter_xall(const float* __restrict__ x,
                             short* __restrict__ hi, short* __restrict__ lo) {
    int idx = blockIdx.x*256 + threadIdx.x;     // col*2048 + n
    int n = idx & (NN-1);
    int col = idx >> 11;
    int c = col & 1, b = (col >> 1) & 31, t = col >> 6;
    float v = x[(size_t)(((size_t)b*TT + t)*NN + n)*CIN + c];
    short h = f2bf(v);
    size_t o = (size_t)col*NN + n;
    hi[o] = h;
    lo[o] = f2bf(v - bf2f(h));
}

// ---------------- W^T split: Wt[j][c] = split(W[rowoff+c][j]) ----------------
__global__ void wsplit_T(const float* __restrict__ W, int rowoff, int Kd,
                         short* __restrict__ hi, short* __restrict__ lo) {
    int id = blockIdx.x*256 + threadIdx.x;      // j*Kd + c
    if (id >= 256*Kd) return;
    int j = id / Kd, c = id - j*Kd;
    float v = W[(size_t)(rowoff + c)*256 + j];
    short h = f2bf(v);
    hi[id] = h;
    lo[id] = f2bf(v - bf2f(h));
}

// ---------------- convX GEMM: f32 out (proven kernel; A strided) --------------
__global__ __launch_bounds__(256, 3) void gc3_gemm(
        const short* __restrict__ Ahi, const short* __restrict__ Alo,
        const short* __restrict__ Bhi, const short* __restrict__ Blo,
        float* __restrict__ Cout, int outStride, int astr) {
    __shared__ short As[12288];
    short* AsHi = As;
    short* AsLo = As + 2048;
    short* BsHi = As + 4096;
    short* BsLo = As + 8192;
    const int t = threadIdx.x;
    const int w = t >> 6, lane = t & 63;
    const int wm = w >> 1, wn = w & 1;
    const int fr = lane & 15, fc = lane >> 4;
    const int rowbase = blockIdx.y * 64;
    const int colbase = blockIdx.x * 128;

    const int rp = t >> 3, ql = t & 7;
    const int qs = ql ^ (rp & 7);
    const int srow = rp*2 + (qs >> 2);
    const int sch  = (qs & 3) * 8;
    const short* aHiS = Ahi + (size_t)(rowbase + srow)*astr + sch;
    const short* aLoS = Alo + (size_t)(rowbase + srow)*astr + sch;
    const short* bHiS = Bhi + (size_t)(colbase + srow)*NN + sch;
    const short* bLoS = Blo + (size_t)(colbase + srow)*NN + sch;
    const size_t bHalf = (size_t)64*NN;

    short* aHiD  = AsHi + t*8;
    short* aLoD  = AsLo + t*8;
    short* bHiD0 = BsHi + t*8;
    short* bHiD1 = BsHi + 2048 + t*8;
    short* bLoD0 = BsLo + t*8;
    short* bLoD1 = BsLo + 2048 + t*8;

    auto ldsoff = [](int row, int f) {
        int rr = row >> 1;
        int q = (((row & 1) << 2) | f) ^ (rr & 7);
        return rr*64 + q*8;
    };
    int aoff[2], boff[4];
#pragma unroll
    for (int m = 0; m < 2; ++m) aoff[m] = ldsoff(wm*32 + m*16 + fr, fc);
#pragma unroll
    for (int n = 0; n < 4; ++n) boff[n] = ldsoff(wn*64 + n*16 + fr, fc);

    f32x4 acc[2][4];
#pragma unroll
    for (int m = 0; m < 2; ++m)
#pragma unroll
        for (int n = 0; n < 4; ++n)
#pragma unroll
            for (int r = 0; r < 4; ++r) acc[m][n][r] = 0.f;

    for (int k0 = 0; k0 < NN; k0 += 32) {
        gload16(aHiS, aHiD);
        gload16(aLoS, aLoD);
        gload16(bHiS, bHiD0);
        gload16(bHiS + bHalf, bHiD1);
        gload16(bLoS, bLoD0);
        gload16(bLoS + bHalf, bLoD1);
        aHiS += 32; aLoS += 32; bHiS += 32; bLoS += 32;
        __syncthreads();
        bfrag ah[2], al[2], bh[4], bl[4];
#pragma unroll
        for (int m = 0; m < 2; ++m) {
            ah[m] = *(const bfrag*)(AsHi + aoff[m]);
            al[m] = *(const bfrag*)(AsLo + aoff[m]);
        }
#pragma unroll
        for (int n = 0; n < 4; ++n) {
            bh[n] = *(const bfrag*)(BsHi + boff[n]);
            bl[n] = *(const bfrag*)(BsLo + boff[n]);
        }
#pragma unroll
        for (int m = 0; m < 2; ++m)
#pragma unroll
            for (int n = 0; n < 4; ++n) {
                acc[m][n] = __builtin_amdgcn_mfma_f32_16x16x32_bf16(ah[m], bh[n], acc[m][n], 0, 0, 0);
                acc[m][n] = __builtin_amdgcn_mfma_f32_16x16x32_bf16(ah[m], bl[n], acc[m][n], 0, 0, 0);
                acc[m][n] = __builtin_amdgcn_mfma_f32_16x16x32_bf16(al[m], bh[n], acc[m][n], 0, 0, 0);
            }
        __syncthreads();
    }
#pragma unroll
    for (int m = 0; m < 2; ++m) {
        const int gr = rowbase + wm*32 + m*16 + fc*4;
#pragma unroll
        for (int n = 0; n < 4; ++n) {
            const int gc = colbase + wn*64 + n*16 + fr;
#pragma unroll
            for (int r = 0; r < 4; ++r)
                Cout[(size_t)(gr + r)*outStride + gc] = acc[m][n][r];
        }
    }
}

// ------- recurrent GEMM: plain bf16, K=6144, 1-barrier counted pipeline -------
// C[2048][PW] packed = A2[2048][6144] @ B2[4096][6144]^T
// 128x256 tile, 8 waves (2Mx4N), BK=64, 3-deep LDS (144KB).
// Per K-tile: vmcnt(6) -> barrier -> stage(t+2) -> 16 ds_read -> 32 MFMA.
__global__ __launch_bounds__(512, 2) void gemm8p(
        const short* __restrict__ A2, const short* __restrict__ B2,
        unsigned int* __restrict__ Cpk, int colstart) {
    __shared__ short lds[3*24576];
    const int tid = threadIdx.x;
    const int w = tid >> 6, lane = tid & 63;
    const int wm = w >> 2, wn = w & 3;
    const int fr = lane & 15, fc = lane >> 4;
    // bijective XCD swizzle (grid counts divisible by 8)
    const int gx = gridDim.x;
    const int nwg = gx * gridDim.y;
    const int fid = blockIdx.y * gx + blockIdx.x;
    const int swz = (fid & 7) * (nwg >> 3) + (fid >> 3);
    const int rowbase = (swz / gx) * 128;
    const int colbase = colstart + (swz % gx) * 256;

    // staging: thread -> one 16B chunk per 8KB sweep; pre-swizzled source
    const int srl = tid >> 3;                    // row within 64-row sweep
    const int sck = (tid & 7) ^ (srl & 7);       // source chunk
    const short* aS0 = A2 + (size_t)(rowbase + srl)*KC + sck*8;
    const short* aS1 = A2 + (size_t)(rowbase + 64 + srl)*KC + sck*8;
    const short* bS0 = B2 + (size_t)(colbase + srl)*KC + sck*8;
    const short* bS1 = B2 + (size_t)(colbase + 64 + srl)*KC + sck*8;
    const short* bS2 = B2 + (size_t)(colbase + 128 + srl)*KC + sck*8;
    const short* bS3 = B2 + (size_t)(colbase + 192 + srl)*KC + sck*8;

    // swizzled fragment read offsets (shorts)
    auto sw = [](int row, int chunk) {
        int c2 = chunk ^ (row & 7);
        return row*64 + c2*8;
    };
    int aoff[4][2], boff[4][2];
#pragma unroll
    for (int m = 0; m < 4; ++m)
#pragma unroll
        for (int kk = 0; kk < 2; ++kk)
            aoff[m][kk] = sw(wm*64 + m*16 + fr, kk*4 + fc);
#pragma unroll
    for (int n = 0; n < 4; ++n)
#pragma unroll
        for (int kk = 0; kk < 2; ++kk)
            boff[n][kk] = 8192 + sw(wn*64 + n*16 + fr, kk*4 + fc);

    bfrag a[4][2], b[4][2];
    f32x4 acc[4][4];
#pragma unroll
    for (int m = 0; m < 4; ++m)
#pragma unroll
        for (int n = 0; n < 4; ++n)
#pragma unroll
            for (int r = 0; r < 4; ++r) acc[m][n][r] = 0.f;

    short* bC = lds;             // compute buffer (tile t)
    short* bN = lds + 24576;     // tile t+1
    short* bP = lds + 49152;     // prefetch dest (tile t+2)

    // prologue: stage tiles 0 and 1
    gload16(aS0, bC + tid*8);            gload16(aS1, bC + 4096 + tid*8);
    gload16(bS0, bC + 8192 + tid*8);     gload16(bS1, bC + 12288 + tid*8);
    gload16(bS2, bC + 16384 + tid*8);    gload16(bS3, bC + 20480 + tid*8);
    gload16(aS0 + 64, bN + tid*8);          gload16(aS1 + 64, bN + 4096 + tid*8);
    gload16(bS0 + 64, bN + 8192 + tid*8);   gload16(bS1 + 64, bN + 12288 + tid*8);
    gload16(bS2 + 64, bN + 16384 + tid*8);  gload16(bS3 + 64, bN + 20480 + tid*8);

    for (int t = 0; t < NT; ++t) {
        // wait: tile t's 6 loads done (tile t+1's 6 may remain in flight)
        if (t < NT-1) { asm volatile("s_waitcnt vmcnt(6)" ::: "memory"); }
        else          { asm volatile("s_waitcnt vmcnt(0)" ::: "memory"); }
        __builtin_amdgcn_s_barrier();     // all waves: buf bC ready; bP free
        // stage tile t+2 into bP (issue-early; lands only after return)
        if (t + 2 < NT) {
            const int toff = (t + 2) * 64;
            gload16(aS0 + toff, bP + tid*8);
            gload16(aS1 + toff, bP + 4096 + tid*8);
            gload16(bS0 + toff, bP + 8192 + tid*8);
            gload16(bS1 + toff, bP + 12288 + tid*8);
            gload16(bS2 + toff, bP + 16384 + tid*8);
            gload16(bS3 + toff, bP + 20480 + tid*8);
        }
        __builtin_amdgcn_sched_barrier(0);
        // read all 16 fragments, then the full 32-MFMA cluster
#pragma unroll
        for (int kk = 0; kk < 2; ++kk) {
#pragma unroll
            for (int m = 0; m < 4; ++m) a[m][kk] = *(const bfrag*)(bC + aoff[m][kk]);
#pragma unroll
            for (int n = 0; n < 4; ++n) b[n][kk] = *(const bfrag*)(bC + boff[n][kk]);
        }
        __builtin_amdgcn_s_setprio(1);
#pragma unroll
        for (int m = 0; m < 4; ++m)
#pragma unroll
            for (int n = 0; n < 4; ++n)
#pragma unroll
                for (int kk = 0; kk < 2; ++kk)
                    acc[m][n] = __builtin_amdgcn_mfma_f32_16x16x32_bf16(
                        a[m][kk], b[n][kk], acc[m][n], 0, 0, 0);
        __builtin_amdgcn_s_setprio(0);
        // rotate buffers
        short* tmp = bC; bC = bN; bN = bP; bP = tmp;
    }
    // epilogue: packed split store. C/D: col = lane&15, row = (lane>>4)*4 + r
#pragma unroll
    for (int m = 0; m < 4; ++m) {
        const int gr0 = rowbase + wm*64 + m*16 + fc*4;
#pragma unroll
        for (int n = 0; n < 4; ++n) {
            const int gc = colbase + wn*64 + n*16 + fr;
#pragma unroll
            for (int r = 0; r < 4; ++r)
                Cpk[(size_t)(gr0 + r)*PW + gc] = packsplit(acc[m][n][r]);
        }
    }
}

// ---------------- MFMA LSTM cell body (shared device fn) ----------------
// P packed (hi|lo). h written to B2 rows: [n]=hi, [2048+n]=lo, [4096+n]=hi.
template<int NCH, bool XEP>
static __device__ __forceinline__ void cell_body(
        const unsigned int* __restrict__ P,
        const float* __restrict__ convX,
        const float* __restrict__ Wx,
        const short* __restrict__ Wthi, const short* __restrict__ Wtlo,
        const float* __restrict__ bias,
        float* __restrict__ cbuf,
        short* __restrict__ hout,
        int tstep, int n0blk, int b) {
    const int t = threadIdx.x;
    const int w = t >> 6, lane = t & 63;
    const int fr = lane & 15, fc = lane >> 4;
    constexpr int KW = NCH*32;

    bfrag bh[4][NCH], bl[4][NCH];
#pragma unroll
    for (int g = 0; g < 4; ++g)
#pragma unroll
        for (int ch = 0; ch < NCH; ++ch) {
            size_t o = (size_t)((g*4 + w)*16 + fr)*KW + ch*32 + fc*8;
            bh[g][ch] = *(const bfrag*)(Wthi + o);
            bl[g][ch] = *(const bfrag*)(Wtlo + o);
        }
    const int k = w*16 + fr;
    float bs[4], wx0[4], wx1[4];
#pragma unroll
    for (int g = 0; g < 4; ++g) {
        bs[g] = bias[g*64 + k];
        if (XEP) { wx0[g] = Wx[g*64 + k]; wx1[g] = Wx[256 + g*64 + k]; }
    }
    int colb[NCH];
#pragma unroll
    for (int ch = 0; ch < NCH; ++ch)
        colb[ch] = (NCH == 2 || ch < 2) ? (2048 + b*64 + ch*32)
                                        : (b*64 + (ch-2)*32);
    const int cc = lane >> 4;
    const size_t crow = (size_t)(b*64 + k)*NN;
    const size_t hrow = (size_t)(b*64 + k)*KC;

    for (int nt = 0; nt < 8; ++nt) {
        const int n0 = n0blk + nt*16;
        bfrag ah[NCH], al[NCH];
#pragma unroll
        for (int ch = 0; ch < NCH; ++ch) {
            const unsigned int* ap = P + (size_t)(n0 + fr)*PW + colb[ch] + fc*8;
            uint4 u0 = *(const uint4*)ap;
            uint4 u1 = *(const uint4*)(ap + 4);
            unsigned int uu[8] = {u0.x,u0.y,u0.z,u0.w,u1.x,u1.y,u1.z,u1.w};
#pragma unroll
            for (int i = 0; i < 8; ++i) {
                ah[ch][i] = (short)(uu[i] & 0xffffu);
                al[ch][i] = (short)(uu[i] >> 16);
            }
        }
        f32x4 acc[4];
#pragma unroll
        for (int g = 0; g < 4; ++g)
#pragma unroll
            for (int r = 0; r < 4; ++r) acc[g][r] = 0.f;
#pragma unroll
        for (int ch = 0; ch < NCH; ++ch)
#pragma unroll
            for (int g = 0; g < 4; ++g) {
                acc[g] = __builtin_amdgcn_mfma_f32_16x16x32_bf16(ah[ch], bh[g][ch], acc[g], 0, 0, 0);
                acc[g] = __builtin_amdgcn_mfma_f32_16x16x32_bf16(ah[ch], bl[g][ch], acc[g], 0, 0, 0);
                acc[g] = __builtin_amdgcn_mfma_f32_16x16x32_bf16(al[ch], bh[g][ch], acc[g], 0, 0, 0);
            }
        const int nb = n0 + cc*4;
        float4 cold = *(const float4*)(cbuf + crow + nb);
        float xa0[4], xa1[4];
        if (XEP) {
#pragma unroll
            for (int r = 0; r < 4; ++r) {
                float2 cx = *(const float2*)(convX + (size_t)(nb + r)*XC + tstep*64 + b*2);
                xa0[r] = cx.x; xa1[r] = cx.y;
            }
        }
        float cn[4], hv[4];
#pragma unroll
        for (int r = 0; r < 4; ++r) {
            float pg[4];
#pragma unroll
            for (int g = 0; g < 4; ++g) {
                pg[g] = acc[g][r] + bs[g];
                if (XEP) pg[g] += xa0[r]*wx0[g] + xa1[r]*wx1[g];
            }
            float gi = 1.f/(1.f + expf(-pg[0]));
            float gf = 1.f/(1.f + expf(-pg[1]));
            float gg = tanhf(pg[2]);
            float go = 1.f/(1.f + expf(-pg[3]));
            float co = (&cold.x)[r];
            cn[r] = gf*co + gi*gg;
            hv[r] = go * tanhf(cn[r]);
        }
        *(float4*)(cbuf + crow + nb) = make_float4(cn[0], cn[1], cn[2], cn[3]);
        short hh[4], hl[4];
#pragma unroll
        for (int r = 0; r < 4; ++r) {
            hh[r] = f2bf(hv[r]);
            hl[r] = f2bf(hv[r] - bf2f(hh[r]));
        }
        short4 h4 = make_short4(hh[0], hh[1], hh[2], hh[3]);
        short4 l4 = make_short4(hl[0], hl[1], hl[2], hl[3]);
        *(short4*)(hout + hrow + nb)        = h4;
        *(short4*)(hout + hrow + 2048 + nb) = l4;
        *(short4*)(hout + hrow + 4096 + nb) = h4;
    }
}

template<int NCH, bool XEP>
__global__ __launch_bounds__(256, 2) void cell_mfma(
        const unsigned int* __restrict__ P,
        const float* __restrict__ convX,
        const float* __restrict__ Wx,
        const short* __restrict__ Wthi, const short* __restrict__ Wtlo,
        const float* __restrict__ bias,
        float* __restrict__ cbuf,
        short* __restrict__ hout,
        int tstep) {
    cell_body<NCH, XEP>(P, convX, Wx, Wthi, Wtlo, bias, cbuf, hout,
                        tstep, blockIdx.x*128, blockIdx.y);
}

// fused: z=0 -> layer-2 cell at t; z=1 -> layer-1 cell at t+1 (independent)
__global__ __launch_bounds__(256, 2) void cell_fused(
        const unsigned int* __restrict__ P,
        const float* __restrict__ convX,
        const float* __restrict__ Wx1,
        const short* __restrict__ Wt2hi, const short* __restrict__ Wt2lo,
        const short* __restrict__ Wt1hi, const short* __restrict__ Wt1lo,
        const float* __restrict__ b2v, const float* __restrict__ b1v,
        float* __restrict__ cs2, float* __restrict__ cs1,
        short* __restrict__ h2out, short* __restrict__ h1out,
        int tnext) {
    if (blockIdx.z == 0)
        cell_body<4, false>(P, nullptr, nullptr, Wt2hi, Wt2lo, b2v, cs2, h2out,
                            0, blockIdx.x*128, blockIdx.y);
    else
        cell_body<2, true>(P, convX, Wx1, Wt1hi, Wt1lo, b1v, cs1, h1out,
                           tnext, blockIdx.x*128, blockIdx.y);
}

// ---------------- out = h2 @ Wp + bp -> [B,HOR,N,1] ----------------
__global__ __launch_bounds__(256) void proj_T(const short* __restrict__ B2,
        const float* __restrict__ Wp, const float* __restrict__ bp,
        float* __restrict__ out) {
    __shared__ float sW[HH*HOR];
    __shared__ float sb[HOR];
    for (int i = threadIdx.x; i < HH*HOR; i += 256) sW[i] = Wp[i];
    if (threadIdx.x < HOR) sb[threadIdx.x] = bp[threadIdx.x];
    __syncthreads();
    int idx = blockIdx.x*256 + threadIdx.x;    // b*2048 + n
    int b = idx >> 11, n = idx & (NN-1);
    float acc[HOR];
#pragma unroll
    for (int j = 0; j < HOR; ++j) acc[j] = sb[j];
    for (int k = 0; k < HH; ++k) {
        size_t row = (size_t)(b*64 + k)*KC + n;
        float h = bf2f(B2[row]) + bf2f(B2[row + 2048]);
#pragma unroll
        for (int j = 0; j < HOR; ++j) acc[j] = fmaf(h, sW[k*HOR + j], acc[j]);
    }
#pragma unroll
    for (int j = 0; j < HOR; ++j)
        out[(size_t)(b*HOR + j)*NN + n] = acc[j];
}

extern "C" void kernel_launch(void* const* d_in, const int* in_sizes, int n_in,
                              void* d_out, int out_size, void* d_ws, size_t ws_size,
                              hipStream_t stream) {
    const float* x  = (const float*)d_in[0];
    const float* E  = (const float*)d_in[1];
    const float* W1 = (const float*)d_in[2];
    const float* b1 = (const float*)d_in[3];
    const float* W2 = (const float*)d_in[4];
    const float* b2 = (const float*)d_in[5];
    const float* Wp = (const float*)d_in[6];
    const float* bp = (const float*)d_in[7];
    float* out = (float*)d_out;

    char* base = (char*)d_ws;
    short* A2     = (short*)base; base += (size_t)NN*KC*2;      // 25.2M
    float* convX  = (float*)base; base += (size_t)NN*XC*4;      // 12.6M
    unsigned int* P = (unsigned int*)base; base += (size_t)NN*PW*4;  // 33.6M
    short* B2     = (short*)base; base += (size_t)PW*KC*2;      // 50.3M
    float* cs1    = (float*)base; base += (size_t)NN*NN*4;      // 16.8M
    float* cs2    = (float*)base; base += (size_t)NN*NN*4;      // 16.8M
    short* Wt2hi  = (short*)base; base += 256*128*2;
    short* Wt2lo  = (short*)base; base += 256*128*2;
    short* Wt1hi  = (short*)base; base += 256*64*2;
    short* Wt1lo  = (short*)base; base += 256*64*2;
    // XallT aliases P (consumed by convX GEMM before P is zeroed)
    short* XThi = (short*)P;
    short* XTlo = XThi + (size_t)XC*NN;
    short* h2out = B2;                        // rows [0,2048)  = h2
    short* h1out = B2 + (size_t)NN*KC;        // rows [2048,4096) = h1

    hipMemsetAsync(cs1, 0, (size_t)NN*NN*4, stream);
    hipMemsetAsync(cs2, 0, (size_t)NN*NN*4, stream);

    compute_A_kernel<<<NN, 256, 0, stream>>>(E, A2);
    wsplit_T<<<(256*128 + 255)/256, 256, 0, stream>>>(W2, 0, 128, Wt2hi, Wt2lo);
    wsplit_T<<<(256*64 + 255)/256, 256, 0, stream>>>(W1, 2, 64, Wt1hi, Wt1lo);
    scatter_xall<<<(XC*NN)/256, 256, 0, stream>>>(x, XThi, XTlo);
    // convX = A @ Xall (once, all timesteps, f32)
    gc3_gemm<<<dim3(XC/128, NN/64), 256, 0, stream>>>(
        A2, A2 + 4096, XThi, XTlo, convX, XC, KC);
    // XT region dead -> zero packed P for first-step reads
    hipMemsetAsync(P, 0, (size_t)NN*PW*4, stream);

    // cell1(0): reads P1=0 + convX(t=0) -> h1 rows of B2
    cell_mfma<2, true><<<dim3(NN/128, BB), 256, 0, stream>>>(
        P, convX, W1, Wt1hi, Wt1lo, b1, cs1, h1out, 0);
    // P1(0) = A @ h1(0)  (cols [2048,4096) only)
    gemm8p<<<dim3(8, 16), 512, 0, stream>>>(A2, B2, P, 2048);

    for (int t = 0; t < TT; ++t) {
        if (t < TT-1) {
            // cell2(t) + cell1(t+1) fused (both read P1(t); independent)
            cell_fused<<<dim3(NN/128, BB, 2), 256, 0, stream>>>(
                P, convX, W1, Wt2hi, Wt2lo, Wt1hi, Wt1lo, b2, b1,
                cs2, cs1, h2out, h1out, t+1);
            // merged GEMM: [P2(t) | P1(t+1)] = A @ [h2(t) | h1(t+1)]
            gemm8p<<<dim3(16, 16), 512, 0, stream>>>(A2, B2, P, 0);
        } else {
            // final step: only cell2(23)
            cell_mfma<4, false><<<dim3(NN/128, BB), 256, 0, stream>>>(
                P, nullptr, nullptr, Wt2hi, Wt2lo, b2, cs2, h2out, 0);
        }
    }
    proj_T<<<(BB*NN)/256, 256, 0, stream>>>(B2, Wp, bp, out);
}

// Round 8
// 3767.584 us; speedup vs baseline: 1.4459x; 1.0632x over previous
//
#include <hip/hip_runtime.h>
#include <hip/hip_bf16.h>
#include <cstddef>
#include <cstdint>

#define NN   2048
#define BB   32
#define TT   24
#define CIN  2
#define HH   64
#define EMBD 16
#define HOR  12
#define XC   (TT*BB*CIN)   // 1536 cols of precomputed A@x
#define PW   4096          // P row width: cols [0,2048)=P2, [2048,4096)=P1
#define KC   6144          // concat K: [hi | hi | lo] x 2048
#define NT   96            // K-tiles of 64

using bfrag  = __attribute__((ext_vector_type(8))) short;   // 8 bf16 = 4 VGPR
using f32x4  = __attribute__((ext_vector_type(4))) float;

static __device__ __forceinline__ short f2bf(float f) {
    __hip_bfloat16 h = __float2bfloat16(f);
    return *reinterpret_cast<short*>(&h);
}
static __device__ __forceinline__ float bf2f(short s) {
    __hip_bfloat16 h;
    *reinterpret_cast<short*>(&h) = s;
    return __bfloat162float(h);
}
static __device__ __forceinline__ unsigned int packsplit(float v) {
    short hb = f2bf(v);
    short lb = f2bf(v - bf2f(hb));
    return (unsigned int)(unsigned short)hb | ((unsigned int)(unsigned short)lb << 16);
}
// fast transcendentals: v_exp_f32 + v_rcp_f32; saturate correctly, no NaN
static __device__ __forceinline__ float fsig(float x) {
    return __builtin_amdgcn_rcpf(1.f + __expf(-x));
}
static __device__ __forceinline__ float ftanh(float x) {
    return 1.f - 2.f*__builtin_amdgcn_rcpf(1.f + __expf(2.f*x));
}

#define AS1 __attribute__((address_space(1)))
#define AS3 __attribute__((address_space(3)))
static __device__ __forceinline__ void gload16(const short* g, short* l) {
    __builtin_amdgcn_global_load_lds((const AS1 void*)g, (AS3 void*)l, 16, 0, 0);
}

// ---------- A = softmax(relu(E E^T)) -> A2 rows [Ahi | Ahi | Alo] (6144) ------
__global__ __launch_bounds__(256) void compute_A_kernel(const float* __restrict__ E,
                                                        short* __restrict__ A2) {
    __shared__ float srow[NN];
    __shared__ float sred[256];
    int row = blockIdx.x;
    float er[EMBD];
#pragma unroll
    for (int k = 0; k < EMBD; ++k) er[k] = E[row*EMBD + k];
    float lmax = -1e30f;
    for (int j = threadIdx.x; j < NN; j += 256) {
        const float* ej = E + j*EMBD;
        float d = 0.f;
#pragma unroll
        for (int k = 0; k < EMBD; ++k) d = fmaf(er[k], ej[k], d);
        d = fmaxf(d, 0.f);
        srow[j] = d;
        lmax = fmaxf(lmax, d);
    }
    sred[threadIdx.x] = lmax;
    __syncthreads();
    for (int s = 128; s > 0; s >>= 1) {
        if (threadIdx.x < s) sred[threadIdx.x] = fmaxf(sred[threadIdx.x], sred[threadIdx.x+s]);
        __syncthreads();
    }
    float rmax = sred[0];
    __syncthreads();
    float lsum = 0.f;
    for (int j = threadIdx.x; j < NN; j += 256) {
        float e = expf(srow[j] - rmax);
        srow[j] = e;
        lsum += e;
    }
    sred[threadIdx.x] = lsum;
    __syncthreads();
    for (int s = 128; s > 0; s >>= 1) {
        if (threadIdx.x < s) sred[threadIdx.x] += sred[threadIdx.x+s];
        __syncthreads();
    }
    float rinv = 1.f / sred[0];
    for (int j = threadIdx.x; j < NN; j += 256) {
        float v = srow[j] * rinv;
        short h = f2bf(v);
        short l = f2bf(v - bf2f(h));
        size_t base = (size_t)row*KC + j;
        A2[base]        = h;
        A2[base + 2048] = h;
        A2[base + 4096] = l;
    }
}

// ---------------- build XallT hi/lo: [col=(t*32+b)*2+c][n] ----------------
__global__ void scatter_xall(const float* __restrict__ x,
                             short* __restrict__ hi, short* __restrict__ lo) {
    int idx = blockIdx.x*256 + threadIdx.x;     // col*2048 + n
    int n = idx & (NN-1);
    int col = idx >> 11;
    int c = col & 1, b = (col >> 1) & 31, t = col >> 6;
    float v = x[(size_t)(((size_t)b*TT + t)*NN + n)*CIN + c];
    short h = f2bf(v);
    size_t o = (size_t)col*NN + n;
    hi[o] = h;
    lo[o] = f2bf(v - bf2f(h));
}

// ---------------- W^T split: Wt[j][c] = split(W[rowoff+c][j]) ----------------
__global__ void wsplit_T(const float* __restrict__ W, int rowoff, int Kd,
                         short* __restrict__ hi, short* __restrict__ lo) {
    int id = blockIdx.x*256 + threadIdx.x;      // j*Kd + c
    if (id >= 256*Kd) return;
    int j = id / Kd, c = id - j*Kd;
    float v = W[(size_t)(rowoff + c)*256 + j];
    short h = f2bf(v);
    hi[id] = h;
    lo[id] = f2bf(v - bf2f(h));
}

// ---------------- convX GEMM: f32 out (proven kernel; A strided) --------------
__global__ __launch_bounds__(256, 3) void gc3_gemm(
        const short* __restrict__ Ahi, const short* __restrict__ Alo,
        const short* __restrict__ Bhi, const short* __restrict__ Blo,
        float* __restrict__ Cout, int outStride, int astr) {
    __shared__ short As[12288];
    short* AsHi = As;
    short* AsLo = As + 2048;
    short* BsHi = As + 4096;
    short* BsLo = As + 8192;
    const int t = threadIdx.x;
    const int w = t >> 6, lane = t & 63;
    const int wm = w >> 1, wn = w & 1;
    const int fr = lane & 15, fc = lane >> 4;
    const int rowbase = blockIdx.y * 64;
    const int colbase = blockIdx.x * 128;

    const int rp = t >> 3, ql = t & 7;
    const int qs = ql ^ (rp & 7);
    const int srow = rp*2 + (qs >> 2);
    const int sch  = (qs & 3) * 8;
    const short* aHiS = Ahi + (size_t)(rowbase + srow)*astr + sch;
    const short* aLoS = Alo + (size_t)(rowbase + srow)*astr + sch;
    const short* bHiS = Bhi + (size_t)(colbase + srow)*NN + sch;
    const short* bLoS = Blo + (size_t)(colbase + srow)*NN + sch;
    const size_t bHalf = (size_t)64*NN;

    short* aHiD  = AsHi + t*8;
    short* aLoD  = AsLo + t*8;
    short* bHiD0 = BsHi + t*8;
    short* bHiD1 = BsHi + 2048 + t*8;
    short* bLoD0 = BsLo + t*8;
    short* bLoD1 = BsLo + 2048 + t*8;

    auto ldsoff = [](int row, int f) {
        int rr = row >> 1;
        int q = (((row & 1) << 2) | f) ^ (rr & 7);
        return rr*64 + q*8;
    };
    int aoff[2], boff[4];
#pragma unroll
    for (int m = 0; m < 2; ++m) aoff[m] = ldsoff(wm*32 + m*16 + fr, fc);
#pragma unroll
    for (int n = 0; n < 4; ++n) boff[n] = ldsoff(wn*64 + n*16 + fr, fc);

    f32x4 acc[2][4];
#pragma unroll
    for (int m = 0; m < 2; ++m)
#pragma unroll
        for (int n = 0; n < 4; ++n)
#pragma unroll
            for (int r = 0; r < 4; ++r) acc[m][n][r] = 0.f;

    for (int k0 = 0; k0 < NN; k0 += 32) {
        gload16(aHiS, aHiD);
        gload16(aLoS, aLoD);
        gload16(bHiS, bHiD0);
        gload16(bHiS + bHalf, bHiD1);
        gload16(bLoS, bLoD0);
        gload16(bLoS + bHalf, bLoD1);
        aHiS += 32; aLoS += 32; bHiS += 32; bLoS += 32;
        __syncthreads();
        bfrag ah[2], al[2], bh[4], bl[4];
#pragma unroll
        for (int m = 0; m < 2; ++m) {
            ah[m] = *(const bfrag*)(AsHi + aoff[m]);
            al[m] = *(const bfrag*)(AsLo + aoff[m]);
        }
#pragma unroll
        for (int n = 0; n < 4; ++n) {
            bh[n] = *(const bfrag*)(BsHi + boff[n]);
            bl[n] = *(const bfrag*)(BsLo + boff[n]);
        }
#pragma unroll
        for (int m = 0; m < 2; ++m)
#pragma unroll
            for (int n = 0; n < 4; ++n) {
                acc[m][n] = __builtin_amdgcn_mfma_f32_16x16x32_bf16(ah[m], bh[n], acc[m][n], 0, 0, 0);
                acc[m][n] = __builtin_amdgcn_mfma_f32_16x16x32_bf16(ah[m], bl[n], acc[m][n], 0, 0, 0);
                acc[m][n] = __builtin_amdgcn_mfma_f32_16x16x32_bf16(al[m], bh[n], acc[m][n], 0, 0, 0);
            }
        __syncthreads();
    }
#pragma unroll
    for (int m = 0; m < 2; ++m) {
        const int gr = rowbase + wm*32 + m*16 + fc*4;
#pragma unroll
        for (int n = 0; n < 4; ++n) {
            const int gc = colbase + wn*64 + n*16 + fr;
#pragma unroll
            for (int r = 0; r < 4; ++r)
                Cout[(size_t)(gr + r)*outStride + gc] = acc[m][n][r];
        }
    }
}

// ------- recurrent GEMM: plain bf16, K=6144, 1-barrier counted pipeline -------
// C[2048][PW] packed = A2[2048][6144] @ B2[4096][6144]^T
// 128x256 tile, 8 waves (2Mx4N), BK=64, 3-deep LDS (144KB).
// Per K-tile: vmcnt(6) -> barrier -> stage(t+2) -> 2 x {8 ds_read, 16 MFMA}.
// Sub-phases desync waves so one wave's MFMA covers another's LDS reads.
__global__ __launch_bounds__(512, 2) void gemm8p(
        const short* __restrict__ A2, const short* __restrict__ B2,
        unsigned int* __restrict__ Cpk, int colstart) {
    __shared__ short lds[3*24576];
    const int tid = threadIdx.x;
    const int w = tid >> 6, lane = tid & 63;
    const int wm = w >> 2, wn = w & 3;
    const int fr = lane & 15, fc = lane >> 4;
    // bijective XCD swizzle (grid counts divisible by 8)
    const int gx = gridDim.x;
    const int nwg = gx * gridDim.y;
    const int fid = blockIdx.y * gx + blockIdx.x;
    const int swz = (fid & 7) * (nwg >> 3) + (fid >> 3);
    const int rowbase = (swz / gx) * 128;
    const int colbase = colstart + (swz % gx) * 256;

    // staging: thread -> one 16B chunk per 8KB sweep; pre-swizzled source
    const int srl = tid >> 3;                    // row within 64-row sweep
    const int sck = (tid & 7) ^ (srl & 7);       // source chunk
    const short* aS0 = A2 + (size_t)(rowbase + srl)*KC + sck*8;
    const short* aS1 = A2 + (size_t)(rowbase + 64 + srl)*KC + sck*8;
    const short* bS0 = B2 + (size_t)(colbase + srl)*KC + sck*8;
    const short* bS1 = B2 + (size_t)(colbase + 64 + srl)*KC + sck*8;
    const short* bS2 = B2 + (size_t)(colbase + 128 + srl)*KC + sck*8;
    const short* bS3 = B2 + (size_t)(colbase + 192 + srl)*KC + sck*8;

    // swizzled fragment read offsets (shorts)
    auto sw = [](int row, int chunk) {
        int c2 = chunk ^ (row & 7);
        return row*64 + c2*8;
    };
    int aoff[4][2], boff[4][2];
#pragma unroll
    for (int m = 0; m < 4; ++m)
#pragma unroll
        for (int kk = 0; kk < 2; ++kk)
            aoff[m][kk] = sw(wm*64 + m*16 + fr, kk*4 + fc);
#pragma unroll
    for (int n = 0; n < 4; ++n)
#pragma unroll
        for (int kk = 0; kk < 2; ++kk)
            boff[n][kk] = 8192 + sw(wn*64 + n*16 + fr, kk*4 + fc);

    bfrag a[4], b[4];
    f32x4 acc[4][4];
#pragma unroll
    for (int m = 0; m < 4; ++m)
#pragma unroll
        for (int n = 0; n < 4; ++n)
#pragma unroll
            for (int r = 0; r < 4; ++r) acc[m][n][r] = 0.f;

    short* bC = lds;             // compute buffer (tile t)
    short* bN = lds + 24576;     // tile t+1
    short* bP = lds + 49152;     // prefetch dest (tile t+2)

    // prologue: stage tiles 0 and 1
    gload16(aS0, bC + tid*8);            gload16(aS1, bC + 4096 + tid*8);
    gload16(bS0, bC + 8192 + tid*8);     gload16(bS1, bC + 12288 + tid*8);
    gload16(bS2, bC + 16384 + tid*8);    gload16(bS3, bC + 20480 + tid*8);
    gload16(aS0 + 64, bN + tid*8);          gload16(aS1 + 64, bN + 4096 + tid*8);
    gload16(bS0 + 64, bN + 8192 + tid*8);   gload16(bS1 + 64, bN + 12288 + tid*8);
    gload16(bS2 + 64, bN + 16384 + tid*8);  gload16(bS3 + 64, bN + 20480 + tid*8);

    for (int t = 0; t < NT; ++t) {
        // wait: tile t's 6 loads done (tile t+1's 6 may remain in flight)
        if (t < NT-1) { asm volatile("s_waitcnt vmcnt(6)" ::: "memory"); }
        else          { asm volatile("s_waitcnt vmcnt(0)" ::: "memory"); }
        __builtin_amdgcn_s_barrier();     // all waves: buf bC ready; bP free
        // stage tile t+2 into bP (issue-early; lands only after return)
        if (t + 2 < NT) {
            const int toff = (t + 2) * 64;
            gload16(aS0 + toff, bP + tid*8);
            gload16(aS1 + toff, bP + 4096 + tid*8);
            gload16(bS0 + toff, bP + 8192 + tid*8);
            gload16(bS1 + toff, bP + 12288 + tid*8);
            gload16(bS2 + toff, bP + 16384 + tid*8);
            gload16(bS3 + toff, bP + 20480 + tid*8);
        }
        __builtin_amdgcn_sched_barrier(0);
        // two sub-phases: {8 ds_read -> 16 MFMA}; no intra-tile barrier
#pragma unroll
        for (int kk = 0; kk < 2; ++kk) {
#pragma unroll
            for (int m = 0; m < 4; ++m) a[m] = *(const bfrag*)(bC + aoff[m][kk]);
#pragma unroll
            for (int n = 0; n < 4; ++n) b[n] = *(const bfrag*)(bC + boff[n][kk]);
            __builtin_amdgcn_sched_barrier(0);
            __builtin_amdgcn_s_setprio(1);
#pragma unroll
            for (int m = 0; m < 4; ++m)
#pragma unroll
                for (int n = 0; n < 4; ++n)
                    acc[m][n] = __builtin_amdgcn_mfma_f32_16x16x32_bf16(
                        a[m], b[n], acc[m][n], 0, 0, 0);
            __builtin_amdgcn_s_setprio(0);
            __builtin_amdgcn_sched_barrier(0);
        }
        // rotate buffers
        short* tmp = bC; bC = bN; bN = bP; bP = tmp;
    }
    // epilogue: packed split store. C/D: col = lane&15, row = (lane>>4)*4 + r
#pragma unroll
    for (int m = 0; m < 4; ++m) {
        const int gr0 = rowbase + wm*64 + m*16 + fc*4;
#pragma unroll
        for (int n = 0; n < 4; ++n) {
            const int gc = colbase + wn*64 + n*16 + fr;
#pragma unroll
            for (int r = 0; r < 4; ++r)
                Cpk[(size_t)(gr0 + r)*PW + gc] = packsplit(acc[m][n][r]);
        }
    }
}

// ---------------- MFMA LSTM cell body (shared device fn) ----------------
// P packed (hi|lo). h written to B2 rows: [n]=hi, [2048+n]=lo, [4096+n]=hi.
template<int NCH, bool XEP>
static __device__ __forceinline__ void cell_body(
        const unsigned int* __restrict__ P,
        const float* __restrict__ convX,
        const float* __restrict__ Wx,
        const short* __restrict__ Wthi, const short* __restrict__ Wtlo,
        const float* __restrict__ bias,
        float* __restrict__ cbuf,
        short* __restrict__ hout,
        int tstep, int n0blk, int b) {
    const int t = threadIdx.x;
    const int w = t >> 6, lane = t & 63;
    const int fr = lane & 15, fc = lane >> 4;
    constexpr int KW = NCH*32;

    bfrag bh[4][NCH], bl[4][NCH];
#pragma unroll
    for (int g = 0; g < 4; ++g)
#pragma unroll
        for (int ch = 0; ch < NCH; ++ch) {
            size_t o = (size_t)((g*4 + w)*16 + fr)*KW + ch*32 + fc*8;
            bh[g][ch] = *(const bfrag*)(Wthi + o);
            bl[g][ch] = *(const bfrag*)(Wtlo + o);
        }
    const int k = w*16 + fr;
    float bs[4], wx0[4], wx1[4];
#pragma unroll
    for (int g = 0; g < 4; ++g) {
        bs[g] = bias[g*64 + k];
        if (XEP) { wx0[g] = Wx[g*64 + k]; wx1[g] = Wx[256 + g*64 + k]; }
    }
    int colb[NCH];
#pragma unroll
    for (int ch = 0; ch < NCH; ++ch)
        colb[ch] = (NCH == 2 || ch < 2) ? (2048 + b*64 + ch*32)
                                        : (b*64 + (ch-2)*32);
    const int cc = lane >> 4;
    const size_t crow = (size_t)(b*64 + k)*NN;
    const size_t hrow = (size_t)(b*64 + k)*KC;

    for (int nt = 0; nt < 8; ++nt) {
        const int n0 = n0blk + nt*16;
        bfrag ah[NCH], al[NCH];
#pragma unroll
        for (int ch = 0; ch < NCH; ++ch) {
            const unsigned int* ap = P + (size_t)(n0 + fr)*PW + colb[ch] + fc*8;
            uint4 u0 = *(const uint4*)ap;
            uint4 u1 = *(const uint4*)(ap + 4);
            unsigned int uu[8] = {u0.x,u0.y,u0.z,u0.w,u1.x,u1.y,u1.z,u1.w};
#pragma unroll
            for (int i = 0; i < 8; ++i) {
                ah[ch][i] = (short)(uu[i] & 0xffffu);
                al[ch][i] = (short)(uu[i] >> 16);
            }
        }
        f32x4 acc[4];
#pragma unroll
        for (int g = 0; g < 4; ++g)
#pragma unroll
            for (int r = 0; r < 4; ++r) acc[g][r] = 0.f;
#pragma unroll
        for (int ch = 0; ch < NCH; ++ch)
#pragma unroll
            for (int g = 0; g < 4; ++g) {
                acc[g] = __builtin_amdgcn_mfma_f32_16x16x32_bf16(ah[ch], bh[g][ch], acc[g], 0, 0, 0);
                acc[g] = __builtin_amdgcn_mfma_f32_16x16x32_bf16(ah[ch], bl[g][ch], acc[g], 0, 0, 0);
                acc[g] = __builtin_amdgcn_mfma_f32_16x16x32_bf16(al[ch], bh[g][ch], acc[g], 0, 0, 0);
            }
        const int nb = n0 + cc*4;
        float4 cold = *(const float4*)(cbuf + crow + nb);
        float xa0[4], xa1[4];
        if (XEP) {
#pragma unroll
            for (int r = 0; r < 4; ++r) {
                float2 cx = *(const float2*)(convX + (size_t)(nb + r)*XC + tstep*64 + b*2);
                xa0[r] = cx.x; xa1[r] = cx.y;
            }
        }
        float cn[4], hv[4];
#pragma unroll
        for (int r = 0; r < 4; ++r) {
            float pg[4];
#pragma unroll
            for (int g = 0; g < 4; ++g) {
                pg[g] = acc[g][r] + bs[g];
                if (XEP) pg[g] += xa0[r]*wx0[g] + xa1[r]*wx1[g];
            }
            float gi = fsig(pg[0]);
            float gf = fsig(pg[1]);
            float gg = ftanh(pg[2]);
            float go = fsig(pg[3]);
            float co = (&cold.x)[r];
            cn[r] = gf*co + gi*gg;
            hv[r] = go * ftanh(cn[r]);
        }
        *(float4*)(cbuf + crow + nb) = make_float4(cn[0], cn[1], cn[2], cn[3]);
        short hh[4], hl[4];
#pragma unroll
        for (int r = 0; r < 4; ++r) {
            hh[r] = f2bf(hv[r]);
            hl[r] = f2bf(hv[r] - bf2f(hh[r]));
        }
        short4 h4 = make_short4(hh[0], hh[1], hh[2], hh[3]);
        short4 l4 = make_short4(hl[0], hl[1], hl[2], hl[3]);
        *(short4*)(hout + hrow + nb)        = h4;
        *(short4*)(hout + hrow + 2048 + nb) = l4;
        *(short4*)(hout + hrow + 4096 + nb) = h4;
    }
}

template<int NCH, bool XEP>
__global__ __launch_bounds__(256, 2) void cell_mfma(
        const unsigned int* __restrict__ P,
        const float* __restrict__ convX,
        const float* __restrict__ Wx,
        const short* __restrict__ Wthi, const short* __restrict__ Wtlo,
        const float* __restrict__ bias,
        float* __restrict__ cbuf,
        short* __restrict__ hout,
        int tstep) {
    cell_body<NCH, XEP>(P, convX, Wx, Wthi, Wtlo, bias, cbuf, hout,
                        tstep, blockIdx.x*128, blockIdx.y);
}

// fused: z=0 -> layer-2 cell at t; z=1 -> layer-1 cell at t+1 (independent)
__global__ __launch_bounds__(256, 2) void cell_fused(
        const unsigned int* __restrict__ P,
        const float* __restrict__ convX,
        const float* __restrict__ Wx1,
        const short* __restrict__ Wt2hi, const short* __restrict__ Wt2lo,
        const short* __restrict__ Wt1hi, const short* __restrict__ Wt1lo,
        const float* __restrict__ b2v, const float* __restrict__ b1v,
        float* __restrict__ cs2, float* __restrict__ cs1,
        short* __restrict__ h2out, short* __restrict__ h1out,
        int tnext) {
    if (blockIdx.z == 0)
        cell_body<4, false>(P, nullptr, nullptr, Wt2hi, Wt2lo, b2v, cs2, h2out,
                            0, blockIdx.x*128, blockIdx.y);
    else
        cell_body<2, true>(P, convX, Wx1, Wt1hi, Wt1lo, b1v, cs1, h1out,
                           tnext, blockIdx.x*128, blockIdx.y);
}

// ---------------- out = h2 @ Wp + bp -> [B,HOR,N,1] ----------------
__global__ __launch_bounds__(256) void proj_T(const short* __restrict__ B2,
        const float* __restrict__ Wp, const float* __restrict__ bp,
        float* __restrict__ out) {
    __shared__ float sW[HH*HOR];
    __shared__ float sb[HOR];
    for (int i = threadIdx.x; i < HH*HOR; i += 256) sW[i] = Wp[i];
    if (threadIdx.x < HOR) sb[threadIdx.x] = bp[threadIdx.x];
    __syncthreads();
    int idx = blockIdx.x*256 + threadIdx.x;    // b*2048 + n
    int b = idx >> 11, n = idx & (NN-1);
    float acc[HOR];
#pragma unroll
    for (int j = 0; j < HOR; ++j) acc[j] = sb[j];
    for (int k = 0; k < HH; ++k) {
        size_t row = (size_t)(b*64 + k)*KC + n;
        float h = bf2f(B2[row]) + bf2f(B2[row + 2048]);
#pragma unroll
        for (int j = 0; j < HOR; ++j) acc[j] = fmaf(h, sW[k*HOR + j], acc[j]);
    }
#pragma unroll
    for (int j = 0; j < HOR; ++j)
        out[(size_t)(b*HOR + j)*NN + n] = acc[j];
}

extern "C" void kernel_launch(void* const* d_in, const int* in_sizes, int n_in,
                              void* d_out, int out_size, void* d_ws, size_t ws_size,
                              hipStream_t stream) {
    const float* x  = (const float*)d_in[0];
    const float* E  = (const float*)d_in[1];
    const float* W1 = (const float*)d_in[2];
    const float* b1 = (const float*)d_in[3];
    const float* W2 = (const float*)d_in[4];
    const float* b2 = (const float*)d_in[5];
    const float* Wp = (const float*)d_in[6];
    const float* bp = (const float*)d_in[7];
    float* out = (float*)d_out;

    char* base = (char*)d_ws;
    short* A2     = (short*)base; base += (size_t)NN*KC*2;      // 25.2M
    float* convX  = (float*)base; base += (size_t)NN*XC*4;      // 12.6M
    unsigned int* P = (unsigned int*)base; base += (size_t)NN*PW*4;  // 33.6M
    short* B2     = (short*)base; base += (size_t)PW*KC*2;      // 50.3M
    float* cs1    = (float*)base; base += (size_t)NN*NN*4;      // 16.8M
    float* cs2    = (float*)base; base += (size_t)NN*NN*4;      // 16.8M
    short* Wt2hi  = (short*)base; base += 256*128*2;
    short* Wt2lo  = (short*)base; base += 256*128*2;
    short* Wt1hi  = (short*)base; base += 256*64*2;
    short* Wt1lo  = (short*)base; base += 256*64*2;
    // XallT aliases P (consumed by convX GEMM before P is zeroed)
    short* XThi = (short*)P;
    short* XTlo = XThi + (size_t)XC*NN;
    short* h2out = B2;                        // rows [0,2048)  = h2
    short* h1out = B2 + (size_t)NN*KC;        // rows [2048,4096) = h1

    hipMemsetAsync(cs1, 0, (size_t)NN*NN*4, stream);
    hipMemsetAsync(cs2, 0, (size_t)NN*NN*4, stream);

    compute_A_kernel<<<NN, 256, 0, stream>>>(E, A2);
    wsplit_T<<<(256*128 + 255)/256, 256, 0, stream>>>(W2, 0, 128, Wt2hi, Wt2lo);
    wsplit_T<<<(256*64 + 255)/256, 256, 0, stream>>>(W1, 2, 64, Wt1hi, Wt1lo);
    scatter_xall<<<(XC*NN)/256, 256, 0, stream>>>(x, XThi, XTlo);
    // convX = A @ Xall (once, all timesteps, f32)
    gc3_gemm<<<dim3(XC/128, NN/64), 256, 0, stream>>>(
        A2, A2 + 4096, XThi, XTlo, convX, XC, KC);
    // XT region dead -> zero packed P for first-step reads
    hipMemsetAsync(P, 0, (size_t)NN*PW*4, stream);

    // cell1(0): reads P1=0 + convX(t=0) -> h1 rows of B2
    cell_mfma<2, true><<<dim3(NN/128, BB), 256, 0, stream>>>(
        P, convX, W1, Wt1hi, Wt1lo, b1, cs1, h1out, 0);
    // P1(0) = A @ h1(0)  (cols [2048,4096) only)
    gemm8p<<<dim3(8, 16), 512, 0, stream>>>(A2, B2, P, 2048);

    for (int t = 0; t < TT; ++t) {
        if (t < TT-1) {
            // cell2(t) + cell1(t+1) fused (both read P1(t); independent)
            cell_fused<<<dim3(NN/128, BB, 2), 256, 0, stream>>>(
                P, convX, W1, Wt2hi, Wt2lo, Wt1hi, Wt1lo, b2, b1,
                cs2, cs1, h2out, h1out, t+1);
            // merged GEMM: [P2(t) | P1(t+1)] = A @ [h2(t) | h1(t+1)]
            gemm8p<<<dim3(16, 16), 512, 0, stream>>>(A2, B2, P, 0);
        } else {
            // final step: only cell2(23)
            cell_mfma<4, false><<<dim3(NN/128, BB), 256, 0, stream>>>(
                P, nullptr, nullptr, Wt2hi, Wt2lo, b2, cs2, h2out, 0);
        }
    }
    proj_T<<<(BB*NN)/256, 256, 0, stream>>>(B2, Wp, bp, out);
}

// Round 9
// 3716.903 us; speedup vs baseline: 1.4656x; 1.0136x over previous
//
#include <hip/hip_runtime.h>
#include <hip/hip_bf16.h>
#include <cstddef>
#include <cstdint>

#define NN   2048
#define BB   32
#define TT   24
#define CIN  2
#define HH   64
#define EMBD 16
#define HOR  12
#define XC   (TT*BB*CIN)   // 1536 cols of precomputed A@x
#define PW   4096          // P row width: cols [0,2048)=P2, [2048,4096)=P1
#define NT2  64            // K-tiles of 32 (K=2048)
#define HOFF ((size_t)2048*NN)   // h1 row offset in Bhi/Blo

using bfrag  = __attribute__((ext_vector_type(8))) short;   // 8 bf16 = 4 VGPR
using f32x4  = __attribute__((ext_vector_type(4))) float;
using f32x16 = __attribute__((ext_vector_type(16))) float;

static __device__ __forceinline__ short f2bf(float f) {
    __hip_bfloat16 h = __float2bfloat16(f);
    return *reinterpret_cast<short*>(&h);
}
static __device__ __forceinline__ float bf2f(short s) {
    __hip_bfloat16 h;
    *reinterpret_cast<short*>(&h) = s;
    return __bfloat162float(h);
}
static __device__ __forceinline__ unsigned int packsplit(float v) {
    short hb = f2bf(v);
    short lb = f2bf(v - bf2f(hb));
    return (unsigned int)(unsigned short)hb | ((unsigned int)(unsigned short)lb << 16);
}
// fast transcendentals: v_exp_f32 + v_rcp_f32; saturate correctly, no NaN
static __device__ __forceinline__ float fsig(float x) {
    return __builtin_amdgcn_rcpf(1.f + __expf(-x));
}
static __device__ __forceinline__ float ftanh(float x) {
    return 1.f - 2.f*__builtin_amdgcn_rcpf(1.f + __expf(2.f*x));
}

#define AS1 __attribute__((address_space(1)))
#define AS3 __attribute__((address_space(3)))
static __device__ __forceinline__ void gload16(const short* g, short* l) {
    __builtin_amdgcn_global_load_lds((const AS1 void*)g, (AS3 void*)l, 16, 0, 0);
}

// ---------- A = softmax(relu(E E^T)) -> split bf16 hi/lo ----------
__global__ __launch_bounds__(256) void compute_A_kernel(const float* __restrict__ E,
                                                        short* __restrict__ Ahi,
                                                        short* __restrict__ Alo) {
    __shared__ float srow[NN];
    __shared__ float sred[256];
    int row = blockIdx.x;
    float er[EMBD];
#pragma unroll
    for (int k = 0; k < EMBD; ++k) er[k] = E[row*EMBD + k];
    float lmax = -1e30f;
    for (int j = threadIdx.x; j < NN; j += 256) {
        const float* ej = E + j*EMBD;
        float d = 0.f;
#pragma unroll
        for (int k = 0; k < EMBD; ++k) d = fmaf(er[k], ej[k], d);
        d = fmaxf(d, 0.f);
        srow[j] = d;
        lmax = fmaxf(lmax, d);
    }
    sred[threadIdx.x] = lmax;
    __syncthreads();
    for (int s = 128; s > 0; s >>= 1) {
        if (threadIdx.x < s) sred[threadIdx.x] = fmaxf(sred[threadIdx.x], sred[threadIdx.x+s]);
        __syncthreads();
    }
    float rmax = sred[0];
    __syncthreads();
    float lsum = 0.f;
    for (int j = threadIdx.x; j < NN; j += 256) {
        float e = expf(srow[j] - rmax);
        srow[j] = e;
        lsum += e;
    }
    sred[threadIdx.x] = lsum;
    __syncthreads();
    for (int s = 128; s > 0; s >>= 1) {
        if (threadIdx.x < s) sred[threadIdx.x] += sred[threadIdx.x+s];
        __syncthreads();
    }
    float rinv = 1.f / sred[0];
    for (int j = threadIdx.x; j < NN; j += 256) {
        float v = srow[j] * rinv;
        short h = f2bf(v);
        Ahi[(size_t)row*NN + j] = h;
        Alo[(size_t)row*NN + j] = f2bf(v - bf2f(h));
    }
}

// ---------------- build XallT hi/lo: [col=(t*32+b)*2+c][n] ----------------
__global__ void scatter_xall(const float* __restrict__ x,
                             short* __restrict__ hi, short* __restrict__ lo) {
    int idx = blockIdx.x*256 + threadIdx.x;     // col*2048 + n
    int n = idx & (NN-1);
    int col = idx >> 11;
    int c = col & 1, b = (col >> 1) & 31, t = col >> 6;
    float v = x[(size_t)(((size_t)b*TT + t)*NN + n)*CIN + c];
    short h = f2bf(v);
    size_t o = (size_t)col*NN + n;
    hi[o] = h;
    lo[o] = f2bf(v - bf2f(h));
}

// ---------------- W^T split: Wt[j][c] = split(W[rowoff+c][j]) ----------------
__global__ void wsplit_T(const float* __restrict__ W, int rowoff, int Kd,
                         short* __restrict__ hi, short* __restrict__ lo) {
    int id = blockIdx.x*256 + threadIdx.x;      // j*Kd + c
    if (id >= 256*Kd) return;
    int j = id / Kd, c = id - j*Kd;
    float v = W[(size_t)(rowoff + c)*256 + j];
    short h = f2bf(v);
    hi[id] = h;
    lo[id] = f2bf(v - bf2f(h));
}

// ---------------- convX GEMM: f32 out (proven kernel) --------------
__global__ __launch_bounds__(256, 3) void gc3_gemm(
        const short* __restrict__ Ahi, const short* __restrict__ Alo,
        const short* __restrict__ Bhi, const short* __restrict__ Blo,
        float* __restrict__ Cout, int outStride) {
    __shared__ short As[12288];
    short* AsHi = As;
    short* AsLo = As + 2048;
    short* BsHi = As + 4096;
    short* BsLo = As + 8192;
    const int t = threadIdx.x;
    const int w = t >> 6, lane = t & 63;
    const int wm = w >> 1, wn = w & 1;
    const int fr = lane & 15, fc = lane >> 4;
    const int rowbase = blockIdx.y * 64;
    const int colbase = blockIdx.x * 128;

    const int rp = t >> 3, ql = t & 7;
    const int qs = ql ^ (rp & 7);
    const int srow = rp*2 + (qs >> 2);
    const int sch  = (qs & 3) * 8;
    const short* aHiS = Ahi + (size_t)(rowbase + srow)*NN + sch;
    const short* aLoS = Alo + (size_t)(rowbase + srow)*NN + sch;
    const short* bHiS = Bhi + (size_t)(colbase + srow)*NN + sch;
    const short* bLoS = Blo + (size_t)(colbase + srow)*NN + sch;
    const size_t bHalf = (size_t)64*NN;

    short* aHiD  = AsHi + t*8;
    short* aLoD  = AsLo + t*8;
    short* bHiD0 = BsHi + t*8;
    short* bHiD1 = BsHi + 2048 + t*8;
    short* bLoD0 = BsLo + t*8;
    short* bLoD1 = BsLo + 2048 + t*8;

    auto ldsoff = [](int row, int f) {
        int rr = row >> 1;
        int q = (((row & 1) << 2) | f) ^ (rr & 7);
        return rr*64 + q*8;
    };
    int aoff[2], boff[4];
#pragma unroll
    for (int m = 0; m < 2; ++m) aoff[m] = ldsoff(wm*32 + m*16 + fr, fc);
#pragma unroll
    for (int n = 0; n < 4; ++n) boff[n] = ldsoff(wn*64 + n*16 + fr, fc);

    f32x4 acc[2][4];
#pragma unroll
    for (int m = 0; m < 2; ++m)
#pragma unroll
        for (int n = 0; n < 4; ++n)
#pragma unroll
            for (int r = 0; r < 4; ++r) acc[m][n][r] = 0.f;

    for (int k0 = 0; k0 < NN; k0 += 32) {
        gload16(aHiS, aHiD);
        gload16(aLoS, aLoD);
        gload16(bHiS, bHiD0);
        gload16(bHiS + bHalf, bHiD1);
        gload16(bLoS, bLoD0);
        gload16(bLoS + bHalf, bLoD1);
        aHiS += 32; aLoS += 32; bHiS += 32; bLoS += 32;
        __syncthreads();
        bfrag ah[2], al[2], bh[4], bl[4];
#pragma unroll
        for (int m = 0; m < 2; ++m) {
            ah[m] = *(const bfrag*)(AsHi + aoff[m]);
            al[m] = *(const bfrag*)(AsLo + aoff[m]);
        }
#pragma unroll
        for (int n = 0; n < 4; ++n) {
            bh[n] = *(const bfrag*)(BsHi + boff[n]);
            bl[n] = *(const bfrag*)(BsLo + boff[n]);
        }
#pragma unroll
        for (int m = 0; m < 2; ++m)
#pragma unroll
            for (int n = 0; n < 4; ++n) {
                acc[m][n] = __builtin_amdgcn_mfma_f32_16x16x32_bf16(ah[m], bh[n], acc[m][n], 0, 0, 0);
                acc[m][n] = __builtin_amdgcn_mfma_f32_16x16x32_bf16(ah[m], bl[n], acc[m][n], 0, 0, 0);
                acc[m][n] = __builtin_amdgcn_mfma_f32_16x16x32_bf16(al[m], bh[n], acc[m][n], 0, 0, 0);
            }
        __syncthreads();
    }
#pragma unroll
    for (int m = 0; m < 2; ++m) {
        const int gr = rowbase + wm*32 + m*16 + fc*4;
#pragma unroll
        for (int n = 0; n < 4; ++n) {
            const int gc = colbase + wn*64 + n*16 + fr;
#pragma unroll
            for (int r = 0; r < 4; ++r)
                Cout[(size_t)(gr + r)*outStride + gc] = acc[m][n][r];
        }
    }
}

// ------- recurrent GEMM: split 3-term, K=2048, BK=32, 32x32x16 frags ---------
// C[2048][PW] packed = (Ah+Al) @ (Bh+Bl)^T (3 terms, Al*Bl dropped)
// 128x256 tile, 8 waves (2Mx4N), 3-deep LDS (144KB), vmcnt(6) counted, 1 barrier.
// LDS buffer (48KB): AsHi[128x32] AsLo BsHi[256x32] BsLo; rows 64B = 4 chunks;
// swizzle chunk ^= (row>>1)&3 (staged via pre-swizzled source).
__global__ __launch_bounds__(512, 2) void gcsplit(
        const short* __restrict__ Ahi, const short* __restrict__ Alo,
        const short* __restrict__ Bhi, const short* __restrict__ Blo,
        unsigned int* __restrict__ Cpk, int colstart) {
    __shared__ short lds[3*24576];
    const int tid = threadIdx.x;
    const int w = tid >> 6, lane = tid & 63;
    const int wm = w >> 2, wn = w & 3;
    const int lr = lane & 31, lh = lane >> 5;
    // bijective XCD swizzle (grid counts divisible by 8)
    const int gx = gridDim.x;
    const int nwg = gx * gridDim.y;
    const int fid = blockIdx.y * gx + blockIdx.x;
    const int swz = (fid & 7) * (nwg >> 3) + (fid >> 3);
    const int rowbase = (swz / gx) * 128;
    const int colbase = colstart + (swz % gx) * 256;

    // staging: thread -> 16B chunk; row = tid>>2, pre-swizzled source chunk
    const int srow = tid >> 2;
    const int sc   = (tid & 3) ^ ((srow >> 1) & 3);
    const short* aHiS  = Ahi + (size_t)(rowbase + srow)*NN + sc*8;
    const short* aLoS  = Alo + (size_t)(rowbase + srow)*NN + sc*8;
    const short* bHiS0 = Bhi + (size_t)(colbase + srow)*NN + sc*8;
    const short* bHiS1 = Bhi + (size_t)(colbase + 128 + srow)*NN + sc*8;
    const short* bLoS0 = Blo + (size_t)(colbase + srow)*NN + sc*8;
    const short* bLoS1 = Blo + (size_t)(colbase + 128 + srow)*NN + sc*8;

    // swizzled fragment read offsets (shorts): row*32 + (c^((row>>1)&3))*8
    auto sw2 = [](int row, int c) {
        return row*32 + (c ^ ((row >> 1) & 3))*8;
    };
    int aoffH[2][2], boffH[2][2];
#pragma unroll
    for (int m = 0; m < 2; ++m)
#pragma unroll
        for (int ks = 0; ks < 2; ++ks)
            aoffH[m][ks] = sw2(wm*64 + m*32 + lr, ks*2 + lh);
#pragma unroll
    for (int n = 0; n < 2; ++n)
#pragma unroll
        for (int ks = 0; ks < 2; ++ks)
            boffH[n][ks] = 8192 + sw2(wn*64 + n*32 + lr, ks*2 + lh);

    f32x16 acc[2][2];
#pragma unroll
    for (int m = 0; m < 2; ++m)
#pragma unroll
        for (int n = 0; n < 2; ++n)
#pragma unroll
            for (int r = 0; r < 16; ++r) acc[m][n][r] = 0.f;

    short* bC = lds;             // compute buffer (tile t)
    short* bN = lds + 24576;     // tile t+1
    short* bP = lds + 49152;     // prefetch dest (tile t+2)

    auto STAGE = [&](short* dst, int koff) {
        gload16(aHiS  + koff, dst + tid*8);
        gload16(aLoS  + koff, dst + 4096  + tid*8);
        gload16(bHiS0 + koff, dst + 8192  + tid*8);
        gload16(bHiS1 + koff, dst + 12288 + tid*8);
        gload16(bLoS0 + koff, dst + 16384 + tid*8);
        gload16(bLoS1 + koff, dst + 20480 + tid*8);
    };
    // prologue: stage tiles 0 and 1
    STAGE(bC, 0);
    STAGE(bN, 32);

    for (int t = 0; t < NT2; ++t) {
        // wait: tile t's 6 loads done (tile t+1's 6 may remain in flight)
        if (t < NT2-1) { asm volatile("s_waitcnt vmcnt(6)" ::: "memory"); }
        else           { asm volatile("s_waitcnt vmcnt(0)" ::: "memory"); }
        __builtin_amdgcn_s_barrier();     // buf bC ready; bP free
        if (t + 2 < NT2) STAGE(bP, (t + 2) * 32);
        __builtin_amdgcn_sched_barrier(0);
#pragma unroll
        for (int ks = 0; ks < 2; ++ks) {
            bfrag ah[2], al[2], bh[2], bl[2];
#pragma unroll
            for (int m = 0; m < 2; ++m) {
                ah[m] = *(const bfrag*)(bC + aoffH[m][ks]);
                al[m] = *(const bfrag*)(bC + 4096 + aoffH[m][ks]);
            }
#pragma unroll
            for (int n = 0; n < 2; ++n) {
                bh[n] = *(const bfrag*)(bC + boffH[n][ks]);
                bl[n] = *(const bfrag*)(bC + 8192 + boffH[n][ks]);
            }
            __builtin_amdgcn_sched_barrier(0);
            __builtin_amdgcn_s_setprio(1);
#pragma unroll
            for (int m = 0; m < 2; ++m)
#pragma unroll
                for (int n = 0; n < 2; ++n) {
                    acc[m][n] = __builtin_amdgcn_mfma_f32_32x32x16_bf16(ah[m], bh[n], acc[m][n], 0, 0, 0);
                    acc[m][n] = __builtin_amdgcn_mfma_f32_32x32x16_bf16(ah[m], bl[n], acc[m][n], 0, 0, 0);
                    acc[m][n] = __builtin_amdgcn_mfma_f32_32x32x16_bf16(al[m], bh[n], acc[m][n], 0, 0, 0);
                }
            __builtin_amdgcn_s_setprio(0);
            __builtin_amdgcn_sched_barrier(0);
        }
        // rotate buffers
        short* tmp = bC; bC = bN; bN = bP; bP = tmp;
    }
    // epilogue: C/D (32x32): col = lane&31, row = (r&3) + 8*(r>>2) + 4*(lane>>5)
#pragma unroll
    for (int m = 0; m < 2; ++m) {
        const int gr0 = rowbase + wm*64 + m*32 + 4*lh;
#pragma unroll
        for (int n = 0; n < 2; ++n) {
            const int gc = colbase + wn*64 + n*32 + lr;
#pragma unroll
            for (int r = 0; r < 16; ++r) {
                int gr = gr0 + (r & 3) + 8*(r >> 2);
                Cpk[(size_t)gr*PW + gc] = packsplit(acc[m][n][r]);
            }
        }
    }
}

// ---------------- MFMA LSTM cell body (shared device fn) ----------------
// P packed (hi|lo). h written to Bhi/Blo rows (b*64+k), stride NN.
template<int NCH, bool XEP>
static __device__ __forceinline__ void cell_body(
        const unsigned int* __restrict__ P,
        const float* __restrict__ convX,
        const float* __restrict__ Wx,
        const short* __restrict__ Wthi, const short* __restrict__ Wtlo,
        const float* __restrict__ bias,
        float* __restrict__ cbuf,
        short* __restrict__ bhi, short* __restrict__ blo,
        int tstep, int n0blk, int b) {
    const int t = threadIdx.x;
    const int w = t >> 6, lane = t & 63;
    const int fr = lane & 15, fc = lane >> 4;
    constexpr int KW = NCH*32;

    bfrag bhw[4][NCH], blw[4][NCH];
#pragma unroll
    for (int g = 0; g < 4; ++g)
#pragma unroll
        for (int ch = 0; ch < NCH; ++ch) {
            size_t o = (size_t)((g*4 + w)*16 + fr)*KW + ch*32 + fc*8;
            bhw[g][ch] = *(const bfrag*)(Wthi + o);
            blw[g][ch] = *(const bfrag*)(Wtlo + o);
        }
    const int k = w*16 + fr;
    float bs[4], wx0[4], wx1[4];
#pragma unroll
    for (int g = 0; g < 4; ++g) {
        bs[g] = bias[g*64 + k];
        if (XEP) { wx0[g] = Wx[g*64 + k]; wx1[g] = Wx[256 + g*64 + k]; }
    }
    int colb[NCH];
#pragma unroll
    for (int ch = 0; ch < NCH; ++ch)
        colb[ch] = (NCH == 2 || ch < 2) ? (2048 + b*64 + ch*32)
                                        : (b*64 + (ch-2)*32);
    const int cc = lane >> 4;
    const size_t crow = (size_t)(b*64 + k)*NN;

    for (int nt = 0; nt < 8; ++nt) {
        const int n0 = n0blk + nt*16;
        bfrag ah[NCH], al[NCH];
#pragma unroll
        for (int ch = 0; ch < NCH; ++ch) {
            const unsigned int* ap = P + (size_t)(n0 + fr)*PW + colb[ch] + fc*8;
            uint4 u0 = *(const uint4*)ap;
            uint4 u1 = *(const uint4*)(ap + 4);
            unsigned int uu[8] = {u0.x,u0.y,u0.z,u0.w,u1.x,u1.y,u1.z,u1.w};
#pragma unroll
            for (int i = 0; i < 8; ++i) {
                ah[ch][i] = (short)(uu[i] & 0xffffu);
                al[ch][i] = (short)(uu[i] >> 16);
            }
        }
        f32x4 acc[4];
#pragma unroll
        for (int g = 0; g < 4; ++g)
#pragma unroll
            for (int r = 0; r < 4; ++r) acc[g][r] = 0.f;
#pragma unroll
        for (int ch = 0; ch < NCH; ++ch)
#pragma unroll
            for (int g = 0; g < 4; ++g) {
                acc[g] = __builtin_amdgcn_mfma_f32_16x16x32_bf16(ah[ch], bhw[g][ch], acc[g], 0, 0, 0);
                acc[g] = __builtin_amdgcn_mfma_f32_16x16x32_bf16(ah[ch], blw[g][ch], acc[g], 0, 0, 0);
                acc[g] = __builtin_amdgcn_mfma_f32_16x16x32_bf16(al[ch], bhw[g][ch], acc[g], 0, 0, 0);
            }
        const int nb = n0 + cc*4;
        float4 cold = *(const float4*)(cbuf + crow + nb);
        float xa0[4], xa1[4];
        if (XEP) {
#pragma unroll
            for (int r = 0; r < 4; ++r) {
                float2 cx = *(const float2*)(convX + (size_t)(nb + r)*XC + tstep*64 + b*2);
                xa0[r] = cx.x; xa1[r] = cx.y;
            }
        }
        float cn[4], hv[4];
#pragma unroll
        for (int r = 0; r < 4; ++r) {
            float pg[4];
#pragma unroll
            for (int g = 0; g < 4; ++g) {
                pg[g] = acc[g][r] + bs[g];
                if (XEP) pg[g] += xa0[r]*wx0[g] + xa1[r]*wx1[g];
            }
            float gi = fsig(pg[0]);
            float gf = fsig(pg[1]);
            float gg = ftanh(pg[2]);
            float go = fsig(pg[3]);
            float co = (&cold.x)[r];
            cn[r] = gf*co + gi*gg;
            hv[r] = go * ftanh(cn[r]);
        }
        *(float4*)(cbuf + crow + nb) = make_float4(cn[0], cn[1], cn[2], cn[3]);
        short hh[4], hl[4];
#pragma unroll
        for (int r = 0; r < 4; ++r) {
            hh[r] = f2bf(hv[r]);
            hl[r] = f2bf(hv[r] - bf2f(hh[r]));
        }
        *(short4*)(bhi + crow + nb) = make_short4(hh[0], hh[1], hh[2], hh[3]);
        *(short4*)(blo + crow + nb) = make_short4(hl[0], hl[1], hl[2], hl[3]);
    }
}

template<int NCH, bool XEP>
__global__ __launch_bounds__(256, 2) void cell_mfma(
        const unsigned int* __restrict__ P,
        const float* __restrict__ convX,
        const float* __restrict__ Wx,
        const short* __restrict__ Wthi, const short* __restrict__ Wtlo,
        const float* __restrict__ bias,
        float* __restrict__ cbuf,
        short* __restrict__ bhi, short* __restrict__ blo,
        int tstep) {
    cell_body<NCH, XEP>(P, convX, Wx, Wthi, Wtlo, bias, cbuf, bhi, blo,
                        tstep, blockIdx.x*128, blockIdx.y);
}

// fused: z=0 -> layer-2 cell at t; z=1 -> layer-1 cell at t+1 (independent)
__global__ __launch_bounds__(256, 2) void cell_fused(
        const unsigned int* __restrict__ P,
        const float* __restrict__ convX,
        const float* __restrict__ Wx1,
        const short* __restrict__ Wt2hi, const short* __restrict__ Wt2lo,
        const short* __restrict__ Wt1hi, const short* __restrict__ Wt1lo,
        const float* __restrict__ b2v, const float* __restrict__ b1v,
        float* __restrict__ cs2, float* __restrict__ cs1,
        short* __restrict__ Bhi, short* __restrict__ Blo,
        int tnext) {
    if (blockIdx.z == 0)
        cell_body<4, false>(P, nullptr, nullptr, Wt2hi, Wt2lo, b2v, cs2,
                            Bhi, Blo, 0, blockIdx.x*128, blockIdx.y);
    else
        cell_body<2, true>(P, convX, Wx1, Wt1hi, Wt1lo, b1v, cs1,
                           Bhi + HOFF, Blo + HOFF, tnext, blockIdx.x*128, blockIdx.y);
}

// ---------------- out = h2 @ Wp + bp -> [B,HOR,N,1] ----------------
__global__ __launch_bounds__(256) void proj_T(const short* __restrict__ Bhi,
        const short* __restrict__ Blo, const float* __restrict__ Wp,
        const float* __restrict__ bp, float* __restrict__ out) {
    __shared__ float sW[HH*HOR];
    __shared__ float sb[HOR];
    for (int i = threadIdx.x; i < HH*HOR; i += 256) sW[i] = Wp[i];
    if (threadIdx.x < HOR) sb[threadIdx.x] = bp[threadIdx.x];
    __syncthreads();
    int idx = blockIdx.x*256 + threadIdx.x;    // b*2048 + n
    int b = idx >> 11, n = idx & (NN-1);
    float acc[HOR];
#pragma unroll
    for (int j = 0; j < HOR; ++j) acc[j] = sb[j];
    for (int k = 0; k < HH; ++k) {
        size_t row = (size_t)(b*64 + k)*NN + n;
        float h = bf2f(Bhi[row]) + bf2f(Blo[row]);
#pragma unroll
        for (int j = 0; j < HOR; ++j) acc[j] = fmaf(h, sW[k*HOR + j], acc[j]);
    }
#pragma unroll
    for (int j = 0; j < HOR; ++j)
        out[(size_t)(b*HOR + j)*NN + n] = acc[j];
}

extern "C" void kernel_launch(void* const* d_in, const int* in_sizes, int n_in,
                              void* d_out, int out_size, void* d_ws, size_t ws_size,
                              hipStream_t stream) {
    const float* x  = (const float*)d_in[0];
    const float* E  = (const float*)d_in[1];
    const float* W1 = (const float*)d_in[2];
    const float* b1 = (const float*)d_in[3];
    const float* W2 = (const float*)d_in[4];
    const float* b2 = (const float*)d_in[5];
    const float* Wp = (const float*)d_in[6];
    const float* bp = (const float*)d_in[7];
    float* out = (float*)d_out;

    char* base = (char*)d_ws;
    short* Ahi    = (short*)base; base += (size_t)NN*NN*2;      // 8.4M
    short* Alo    = (short*)base; base += (size_t)NN*NN*2;      // 8.4M
    float* convX  = (float*)base; base += (size_t)NN*XC*4;      // 12.6M
    unsigned int* P = (unsigned int*)base; base += (size_t)NN*PW*4;  // 33.6M
    short* Bhi    = (short*)base; base += (size_t)2*NN*NN*2;    // 16.8M (h2|h1)
    short* Blo    = (short*)base; base += (size_t)2*NN*NN*2;    // 16.8M
    float* cs1    = (float*)base; base += (size_t)NN*NN*4;      // 16.8M
    float* cs2    = (float*)base; base += (size_t)NN*NN*4;      // 16.8M
    short* Wt2hi  = (short*)base; base += 256*128*2;
    short* Wt2lo  = (short*)base; base += 256*128*2;
    short* Wt1hi  = (short*)base; base += 256*64*2;
    short* Wt1lo  = (short*)base; base += 256*64*2;
    // XallT aliases P (consumed by convX GEMM before P is zeroed)
    short* XThi = (short*)P;
    short* XTlo = XThi + (size_t)XC*NN;

    hipMemsetAsync(cs1, 0, (size_t)NN*NN*4, stream);
    hipMemsetAsync(cs2, 0, (size_t)NN*NN*4, stream);

    compute_A_kernel<<<NN, 256, 0, stream>>>(E, Ahi, Alo);
    wsplit_T<<<(256*128 + 255)/256, 256, 0, stream>>>(W2, 0, 128, Wt2hi, Wt2lo);
    wsplit_T<<<(256*64 + 255)/256, 256, 0, stream>>>(W1, 2, 64, Wt1hi, Wt1lo);
    scatter_xall<<<(XC*NN)/256, 256, 0, stream>>>(x, XThi, XTlo);
    // convX = A @ Xall (once, all timesteps, f32)
    gc3_gemm<<<dim3(XC/128, NN/64), 256, 0, stream>>>(
        Ahi, Alo, XThi, XTlo, convX, XC);
    // XT region dead -> zero packed P for first-step reads
    hipMemsetAsync(P, 0, (size_t)NN*PW*4, stream);

    // cell1(0): reads P1=0 + convX(t=0) -> h1 rows of Bhi/Blo
    cell_mfma<2, true><<<dim3(NN/128, BB), 256, 0, stream>>>(
        P, convX, W1, Wt1hi, Wt1lo, b1, cs1, Bhi + HOFF, Blo + HOFF, 0);
    // P1(0) = A @ h1(0)  (cols [2048,4096) only)
    gcsplit<<<dim3(8, 16), 512, 0, stream>>>(Ahi, Alo, Bhi, Blo, P, 2048);

    for (int t = 0; t < TT; ++t) {
        if (t < TT-1) {
            // cell2(t) + cell1(t+1) fused (both read P1(t); independent)
            cell_fused<<<dim3(NN/128, BB, 2), 256, 0, stream>>>(
                P, convX, W1, Wt2hi, Wt2lo, Wt1hi, Wt1lo, b2, b1,
                cs2, cs1, Bhi, Blo, t+1);
            // merged GEMM: [P2(t) | P1(t+1)] = A @ [h2(t) | h1(t+1)]
            gcsplit<<<dim3(16, 16), 512, 0, stream>>>(Ahi, Alo, Bhi, Blo, P, 0);
        } else {
            // final step: only cell2(23)
            cell_mfma<4, false><<<dim3(NN/128, BB), 256, 0, stream>>>(
                P, nullptr, nullptr, Wt2hi, Wt2lo, b2, cs2, Bhi, Blo, 0);
        }
    }
    proj_T<<<(BB*NN)/256, 256, 0, stream>>>(Bhi, Blo, Wp, bp, out);
}